// Round 1
// baseline (1652.452 us; speedup 1.0000x reference)
//
#include <hip/hip_runtime.h>

// ---------------- problem dims ----------------
#define HH 230
#define DD 460            // 2H
#define PPn 512
#define QQn 64
#define BBn 32
#define G4 920            // 4H
#define K1 1840           // 8H
#define KP1 1856          // padded K for big GEMM
#define MRn 16384         // B*P
#define KP3 480           // padded K for ptr GEMM
#define LDFB 480

typedef _Float16 f16;
typedef f16 half2v __attribute__((ext_vector_type(2)));
typedef short bf16x8_t __attribute__((ext_vector_type(8)));
typedef float f32x4_t __attribute__((ext_vector_type(4)));

// ---------------- helpers ----------------
__device__ __forceinline__ float sigm(float x) { return 1.0f / (1.0f + __expf(-x)); }
__device__ __forceinline__ float tanhfast(float x) { return 1.0f - 2.0f / (__expf(2.0f * x) + 1.0f); }

__device__ __forceinline__ unsigned short f2bf(float x) {
  unsigned int u = __builtin_bit_cast(unsigned int, x);
  unsigned int r = (u + 0x7fffu + ((u >> 16) & 1u)) >> 16;
  return (unsigned short)r;
}
__device__ __forceinline__ float bf2f(unsigned short h) {
  unsigned int u = ((unsigned int)h) << 16;
  return __builtin_bit_cast(float, u);
}

__device__ __forceinline__ float dot2f(half2v a, half2v b, float c) {
#if __has_builtin(__builtin_amdgcn_fdot2)
  return __builtin_amdgcn_fdot2(a, b, c, false);
#else
  return c + (float)a.x * (float)b.x + (float)a.y * (float)b.y;
#endif
}

// ---------------- ws layout (bytes) ----------------
static constexpr size_t SZ_X   = (size_t)MRn * G4 * 4;          // 60,293,120
static constexpr size_t OFF_XF = 0;
static constexpr size_t OFF_XB = OFF_XF + SZ_X;
static constexpr size_t OFF_FI = OFF_XB + SZ_X;                 // final_in bf16 [MR][1856]
static constexpr size_t SZ_FI  = (size_t)MRn * KP1 * 2;
static constexpr size_t OFF_Y  = OFF_FI;                         // overlay (after FI dead)
static constexpr size_t OFF_FB = OFF_FI + (size_t)MRn * DD * 4;  // overlay: final bf16 [MR][480]
static constexpr size_t OFF_WFP = OFF_FI + SZ_FI;                // [1024][1856] bf16
static constexpr size_t SZ_WP1  = (size_t)1024 * KP1 * 2;
static constexpr size_t OFF_WBP = OFF_WFP + SZ_WP1;
static constexpr size_t OFF_W2P = OFF_WBP + SZ_WP1;              // [512][480] bf16
static constexpr size_t SZ_W2P  = (size_t)512 * KP3 * 2;
static constexpr size_t OFF_WPF = OFF_W2P + SZ_W2P;              // packed Whh f16x2 [115][920]
static constexpr size_t SZ_WPK  = (size_t)115 * G4 * 4;
static constexpr size_t OFF_WPB = ((OFF_WPF + SZ_WPK + 255) & ~(size_t)255);
static constexpr size_t OFF_WTF = ((OFF_WPB + SZ_WPK + 255) & ~(size_t)255); // b_Wih^T [460][920] f32
static constexpr size_t SZ_WT   = (size_t)DD * G4 * 4;
static constexpr size_t OFF_WTB = OFF_WTF + SZ_WT;
static constexpr size_t OFF_BIASF = OFF_WTB + SZ_WT;
static constexpr size_t OFF_BIASB = ((OFF_BIASF + G4 * 4 + 255) & ~(size_t)255);
static constexpr size_t OFF_SP  = ((OFF_BIASB + G4 * 4 + 255) & ~(size_t)255); // [P*B] f32
static constexpr size_t OFF_SQ  = OFF_SP + (size_t)PPn * BBn * 4;
static constexpr size_t OFF_S1  = OFF_SQ + (size_t)QQn * BBn * 4;
static constexpr size_t OFF_AL1 = OFF_S1 + (size_t)MRn * 4;
static constexpr size_t OFF_C1  = OFF_AL1 + (size_t)MRn * 4;
static constexpr size_t OFF_H0A = ((OFF_C1 + (size_t)BBn * DD * 4 + 255) & ~(size_t)255);
static constexpr size_t OFF_HR  = ((OFF_H0A + (size_t)BBn * DD * 4 + 255) & ~(size_t)255);
static constexpr size_t OFF_S2  = ((OFF_HR + (size_t)BBn * DD * 4 + 255) & ~(size_t)255);
// total ~194.3 MB

// ---------------- prep kernels ----------------
__global__ __launch_bounds__(256) void k_pad_wih(const float* __restrict__ Wf, const float* __restrict__ Wb,
                                                 unsigned short* __restrict__ Pf, unsigned short* __restrict__ Pb) {
  size_t idx = (size_t)blockIdx.x * 256 + threadIdx.x;   // < 1024*1856
  int n = (int)(idx / KP1), k = (int)(idx % KP1);
  const float* W = blockIdx.y ? Wb : Wf;
  unsigned short* Pp = blockIdx.y ? Pb : Pf;
  float v = (n < G4 && k < K1) ? W[(size_t)n * K1 + k] : 0.f;
  Pp[idx] = f2bf(v);
}

__global__ __launch_bounds__(256) void k_pad_w2a(const float* __restrict__ W, unsigned short* __restrict__ Pq) {
  size_t idx = (size_t)blockIdx.x * 256 + threadIdx.x;   // < 512*480
  int n = (int)(idx / KP3), k = (int)(idx % KP3);
  float v = (n < DD && k < DD) ? W[(size_t)n * G4 + k] : 0.f;
  Pq[idx] = f2bf(v);
}

__global__ __launch_bounds__(256) void k_pack_whh(const float* __restrict__ Wf, const float* __restrict__ Wb,
                                                  unsigned int* __restrict__ Pf, unsigned int* __restrict__ Pb) {
  int idx = blockIdx.x * 256 + threadIdx.x;              // < 115*920
  if (idx >= 115 * G4) return;
  int kk = idx / G4, row = idx % G4;
  const float* W = blockIdx.y ? Wb : Wf;
  unsigned int* Pp = blockIdx.y ? Pb : Pf;
  half2v h; h.x = (f16)W[(size_t)row * HH + 2 * kk]; h.y = (f16)W[(size_t)row * HH + 2 * kk + 1];
  Pp[idx] = __builtin_bit_cast(unsigned int, h);
}

__global__ __launch_bounds__(256) void k_pack_bwih(const float* __restrict__ Wf, const float* __restrict__ Wb,
                                                   float* __restrict__ Tf, float* __restrict__ Tb) {
  int idx = blockIdx.x * 256 + threadIdx.x;              // < 460*920
  if (idx >= DD * G4) return;
  int d = idx / G4, row = idx % G4;
  const float* W = blockIdx.y ? Wb : Wf;
  float* T = blockIdx.y ? Tb : Tf;
  T[idx] = W[(size_t)row * DD + d];
}

__global__ __launch_bounds__(256) void k_bias(const float* __restrict__ bihF, const float* __restrict__ bhhF,
                                              const float* __restrict__ bihB, const float* __restrict__ bhhB,
                                              float* __restrict__ biasF, float* __restrict__ biasB) {
  int i = blockIdx.x * 256 + threadIdx.x;
  if (i < G4) {
    if (blockIdx.y == 0) biasF[i] = bihF[i] + bhhF[i];
    else biasB[i] = bihB[i] + bhhB[i];
  }
}

__global__ __launch_bounds__(256) void k_fbpad(unsigned short* __restrict__ FB) {
  int i = blockIdx.x * 256 + threadIdx.x;                // < 16384*20
  int r = i / 20, j = i % 20;
  FB[(size_t)r * LDFB + DD + j] = 0;
}

// sp[p*B+b] = p_features row . w   (also used for sq)
__global__ __launch_bounds__(256) void k_rowdot(const float* __restrict__ M, const float* __restrict__ w,
                                                float* __restrict__ out) {
  int r = blockIdx.x * 4 + (threadIdx.x >> 6);
  int lane = threadIdx.x & 63;
  const float* row = M + (size_t)r * DD;
  float acc = 0.f;
  for (int d = lane; d < DD; d += 64) acc += row[d] * w[d];
#pragma unroll
  for (int d = 1; d < 64; d <<= 1) acc += __shfl_xor(acc, d, 64);
  if (lane == 0) out[r] = acc;
}

// ---------------- fused attention -> final_in (bf16) ----------------
__global__ __launch_bounds__(256) void k_attn(const float* __restrict__ p_feat, const float* __restrict__ q_feat,
                                              const float* __restrict__ score_w, const float* __restrict__ score_b,
                                              const float* __restrict__ sp, const float* __restrict__ sq,
                                              unsigned short* __restrict__ FIp) {
  __shared__ half2v q_s[64 * 230];
  __shared__ half2v p_s[32 * 230];
  __shared__ half2v wpq[230];
  __shared__ float sq_s[64];
  __shared__ float u_row[64];
  __shared__ __align__(16) float w_row[64];
  __shared__ float mxs[1];

  int tid = threadIdx.x;
  int b = blockIdx.y;
  int p0 = blockIdx.x * 32;

  for (int i = tid; i < 230; i += 256) {
    half2v w; w.x = (f16)score_w[2 * DD + 2 * i]; w.y = (f16)score_w[2 * DD + 2 * i + 1];
    wpq[i] = w;
  }
  for (int i = tid; i < 64; i += 256) sq_s[i] = sq[i * BBn + b];
  for (int q = 0; q < 64; q++) {
    for (int i = tid; i < 230; i += 256) {
      float2 f2 = *(const float2*)(q_feat + ((size_t)(q * BBn + b)) * DD + 2 * i);
      half2v v; v.x = (f16)f2.x; v.y = (f16)f2.y;
      q_s[q * 230 + i] = v;
    }
  }
  for (int pl = 0; pl < 32; pl++) {
    for (int i = tid; i < 230; i += 256) {
      float2 f2 = *(const float2*)(p_feat + ((size_t)((p0 + pl) * BBn + b)) * DD + 2 * i);
      half2v v; v.x = (f16)f2.x; v.y = (f16)f2.y;
      p_s[pl * 230 + i] = v;
    }
  }
  __syncthreads();

  float sbias = score_b[0];
  int lane = tid & 63, wv = tid >> 6;
  int myq = tid >> 2, quarter = tid & 3;
  int kb = quarter * 58;
  int ke = (kb + 58 < 230) ? (kb + 58) : 230;

  for (int pl = 0; pl < 32; pl++) {
    // ---- u-dot over d for all q (4 lanes per q) ----
    float acc = 0.f;
    const half2v* prow = p_s + pl * 230;
    const half2v* qrow = q_s + myq * 230;
    for (int k = kb; k < ke; k++) {
      half2v pw = prow[k] * wpq[k];
      acc = dot2f(pw, qrow[k], acc);
    }
    acc += __shfl_xor(acc, 1, 64);
    acc += __shfl_xor(acc, 2, 64);
    if (quarter == 0) u_row[myq] = acc + sp[(p0 + pl) * BBn + b] + sq_s[myq] + sbias;
    __syncthreads();
    // ---- softmax over q (wave 0) ----
    if (wv == 0) {
      float v = u_row[lane];
      float m = v;
#pragma unroll
      for (int d = 1; d < 64; d <<= 1) m = fmaxf(m, __shfl_xor(m, d, 64));
      float e = __expf(v - m);
      float s = e;
#pragma unroll
      for (int d = 1; d < 64; d <<= 1) s += __shfl_xor(s, d, 64);
      w_row[lane] = e / s;
      if (lane == 0) mxs[0] = m;   // c2q = max_q u
    }
    __syncthreads();
    // ---- PV + write final_in ----
    if (tid < 230) {
      float c2q = mxs[0];
      half2v pv = p_s[pl * 230 + tid];
      float nux = 0.f, nuy = 0.f;
      for (int q = 0; q < 64; q += 4) {
        float4 wq = *(const float4*)&w_row[q];
        half2v q0 = q_s[(q + 0) * 230 + tid];
        half2v q1 = q_s[(q + 1) * 230 + tid];
        half2v q2 = q_s[(q + 2) * 230 + tid];
        half2v q3 = q_s[(q + 3) * 230 + tid];
        nux = fmaf(wq.x, (float)q0.x, nux); nuy = fmaf(wq.x, (float)q0.y, nuy);
        nux = fmaf(wq.y, (float)q1.x, nux); nuy = fmaf(wq.y, (float)q1.y, nuy);
        nux = fmaf(wq.z, (float)q2.x, nux); nuy = fmaf(wq.z, (float)q2.y, nuy);
        nux = fmaf(wq.w, (float)q3.x, nux); nuy = fmaf(wq.w, (float)q3.y, nuy);
      }
      float px = (float)pv.x, py = (float)pv.y;
      size_t rr = (size_t)(b * PPn + p0 + pl);
      unsigned short* o = FIp + rr * KP1 + 2 * tid;
      *(unsigned int*)(o +    0) = (unsigned int)f2bf(px)            | ((unsigned int)f2bf(py) << 16);
      *(unsigned int*)(o +  460) = (unsigned int)f2bf(c2q * px)      | ((unsigned int)f2bf(c2q * py) << 16);
      *(unsigned int*)(o +  920) = (unsigned int)f2bf(px * nux)      | ((unsigned int)f2bf(py * nuy) << 16);
      *(unsigned int*)(o + 1380) = (unsigned int)f2bf(c2q * px * px) | ((unsigned int)f2bf(c2q * py * py) << 16);
    } else if (tid < 238) {
      int j = tid - 230;
      size_t rr = (size_t)(b * PPn + p0 + pl);
      *(unsigned int*)(FIp + rr * KP1 + 1840 + 2 * j) = 0u;  // K pad
    }
    __syncthreads();
  }
}

// ---------------- bf16 MFMA GEMM: C[M][Nreal] = A[M][K] * Bw[N][K]^T (+bias) ----------------
__global__ __launch_bounds__(256, 2) void k_gemm(const unsigned short* __restrict__ A, int lda,
                                                 const unsigned short* __restrict__ Bw, int ldb,
                                                 float* __restrict__ C, int ldc,
                                                 int Nreal, int Ktiles, const float* __restrict__ bias) {
  __shared__ unsigned short As[128 * 32];
  __shared__ unsigned short Bs[128 * 32];
  int tid = threadIdx.x;
  int m0 = blockIdx.x * 128, n0 = blockIdx.y * 128;
  int wv = tid >> 6, lane = tid & 63;
  int wr = wv >> 1, wc = wv & 1;
  int laneM = lane & 15, laneK = lane >> 4;

  f32x4_t acc[4][4];
#pragma unroll
  for (int i = 0; i < 4; i++)
#pragma unroll
    for (int j = 0; j < 4; j++) acc[i][j] = (f32x4_t){0.f, 0.f, 0.f, 0.f};

  int row0 = tid >> 2, ch0 = tid & 3;
  int row1 = (256 + tid) >> 2, ch1 = tid & 3;
  const unsigned short* a0 = A + (size_t)(m0 + row0) * lda + ch0 * 8;
  const unsigned short* a1 = A + (size_t)(m0 + row1) * lda + ch1 * 8;
  const unsigned short* b0 = Bw + (size_t)(n0 + row0) * ldb + ch0 * 8;
  const unsigned short* b1 = Bw + (size_t)(n0 + row1) * ldb + ch1 * 8;

  for (int kt = 0; kt < Ktiles; kt++) {
    uint4 av0 = *(const uint4*)a0;
    uint4 av1 = *(const uint4*)a1;
    uint4 bv0 = *(const uint4*)b0;
    uint4 bv1 = *(const uint4*)b1;
    a0 += 32; a1 += 32; b0 += 32; b1 += 32;
    __syncthreads();
    *(uint4*)(As + (size_t)tid * 8)         = av0;
    *(uint4*)(As + (size_t)(256 + tid) * 8) = av1;
    *(uint4*)(Bs + (size_t)tid * 8)         = bv0;
    *(uint4*)(Bs + (size_t)(256 + tid) * 8) = bv1;
    __syncthreads();
    bf16x8_t af[4], bfr[4];
#pragma unroll
    for (int mi = 0; mi < 4; mi++)
      af[mi] = *(const bf16x8_t*)(As + (size_t)(wr * 64 + mi * 16 + laneM) * 32 + laneK * 8);
#pragma unroll
    for (int ni = 0; ni < 4; ni++)
      bfr[ni] = *(const bf16x8_t*)(Bs + (size_t)(wc * 64 + ni * 16 + laneM) * 32 + laneK * 8);
#pragma unroll
    for (int mi = 0; mi < 4; mi++)
#pragma unroll
      for (int ni = 0; ni < 4; ni++)
        acc[mi][ni] = __builtin_amdgcn_mfma_f32_16x16x32_bf16(af[mi], bfr[ni], acc[mi][ni], 0, 0, 0);
  }
#pragma unroll
  for (int mi = 0; mi < 4; mi++)
#pragma unroll
    for (int ni = 0; ni < 4; ni++) {
      int ccol = n0 + wc * 64 + ni * 16 + laneM;
      if (ccol < Nreal) {
        float bv = bias ? bias[ccol] : 0.f;
#pragma unroll
        for (int j = 0; j < 4; j++) {
          int crow = m0 + wr * 64 + mi * 16 + laneK * 4 + j;
          C[(size_t)crow * ldc + ccol] = acc[mi][ni][j] + bv;
        }
      }
    }
}

// ---------------- persistent BiLSTM recurrence ----------------
// 64 WGs: (dir, batch). Whh register-resident as f16 pairs. h in LDS.
__global__ __launch_bounds__(512, 2) void k_recur(const unsigned int* __restrict__ WPf,
                                                  const unsigned int* __restrict__ WPb,
                                                  const float* __restrict__ Xf, const float* __restrict__ Xb,
                                                  float* __restrict__ outF, unsigned short* __restrict__ FB) {
  __shared__ unsigned int h2[2][116];
  __shared__ float abuf[232];
  int tid = threadIdx.x;
  int dir = blockIdx.x >> 5, b = blockIdx.x & 31;
  const unsigned int* WP = dir ? WPb : WPf;
  const float* X = dir ? Xb : Xf;

  bool isA = tid < 230;
  bool isB = (tid >= 256) && (tid < 486);
  bool act = isA || isB;
  int u = isA ? tid : (tid - 256);
  int row0 = isA ? u : (HH + u);              // i-row | f-row
  int row1 = isA ? (2 * HH + u) : (3 * HH + u); // g-row | o-row

  half2v w0[115], w1[115];
  if (act) {
#pragma unroll
    for (int k = 0; k < 115; k++) {
      w0[k] = __builtin_bit_cast(half2v, WP[k * G4 + row0]);
      w1[k] = __builtin_bit_cast(half2v, WP[k * G4 + row1]);
    }
  }
  for (int i = tid; i < 116; i += 512) { h2[0][i] = 0u; h2[1][i] = 0u; }

  int col0 = u + (isB ? HH : 0);
  int col1 = col0 + 2 * HH;
  float x0 = 0.f, x1 = 0.f;
  if (act) {
    int t0 = dir ? (PPn - 1) : 0;
    const float* xr = X + (size_t)(b * PPn + t0) * G4;
    x0 = xr[col0]; x1 = xr[col1];
  }
  float c = 0.f;
  __syncthreads();

  for (int s = 0; s < PPn; s++) {
    int t = dir ? (PPn - 1 - s) : s;
    float acc0 = x0, acc1 = x1;
    if (act && s < PPn - 1) {
      int tn = dir ? (PPn - 2 - s) : (s + 1);
      const float* xr = X + (size_t)(b * PPn + tn) * G4;
      x0 = xr[col0]; x1 = xr[col1];
    }
    const unsigned int* hb = h2[s & 1];
    if (act) {
#pragma unroll
      for (int ch = 0; ch < 28; ch++) {
        uint4 hv = *(const uint4*)(hb + ch * 4);
        half2v ha = __builtin_bit_cast(half2v, hv.x);
        half2v hbv = __builtin_bit_cast(half2v, hv.y);
        half2v hc = __builtin_bit_cast(half2v, hv.z);
        half2v hd = __builtin_bit_cast(half2v, hv.w);
        acc0 = dot2f(w0[ch * 4 + 0], ha, acc0);  acc1 = dot2f(w1[ch * 4 + 0], ha, acc1);
        acc0 = dot2f(w0[ch * 4 + 1], hbv, acc0); acc1 = dot2f(w1[ch * 4 + 1], hbv, acc1);
        acc0 = dot2f(w0[ch * 4 + 2], hc, acc0);  acc1 = dot2f(w1[ch * 4 + 2], hc, acc1);
        acc0 = dot2f(w0[ch * 4 + 3], hd, acc0);  acc1 = dot2f(w1[ch * 4 + 3], hd, acc1);
      }
      uint2 hv2 = *(const uint2*)(hb + 112);
      half2v ha = __builtin_bit_cast(half2v, hv2.x);
      half2v hbv = __builtin_bit_cast(half2v, hv2.y);
      acc0 = dot2f(w0[112], ha, acc0);  acc1 = dot2f(w1[112], ha, acc1);
      acc0 = dot2f(w0[113], hbv, acc0); acc1 = dot2f(w1[113], hbv, acc1);
      half2v hc = __builtin_bit_cast(half2v, hb[114]);
      acc0 = dot2f(w0[114], hc, acc0);  acc1 = dot2f(w1[114], hc, acc1);
    }
    float ff = 0.f, oo = 0.f;
    if (isA) {
      abuf[u] = sigm(acc0) * tanhfast(acc1);   // sig(i)*tanh(g)
    }
    if (isB) { ff = sigm(acc0); oo = sigm(acc1); }
    __syncthreads();
    if (isB) {
      c = ff * c + abuf[u];
      float hval = oo * tanhfast(c);
      f16* hw = (f16*)(&h2[(s + 1) & 1][0]);
      hw[u] = (f16)hval;
      size_t ro = (size_t)(b * PPn + t);
      outF[ro * DD + dir * HH + u] = hval;
      FB[ro * LDFB + dir * HH + u] = f2bf(hval);
    }
    __syncthreads();
  }
}

// ---------------- ptr scores ----------------
__global__ __launch_bounds__(256) void k_score(const float* __restrict__ Yv, const float* __restrict__ hR,
                                               const float* __restrict__ w1a, const float* __restrict__ w1b,
                                               float* __restrict__ out) {
  int r = blockIdx.x * 4 + (threadIdx.x >> 6);
  int lane = threadIdx.x & 63;
  const float* row = Yv + (size_t)r * DD;
  const float* hrow = hR ? (hR + (size_t)(r >> 9) * DD) : nullptr;
  float acc = 0.f;
  for (int e = lane; e < DD; e += 64) {
    float v = row[e];
    if (hrow) v += hrow[e];
    acc += tanhfast(v) * w1a[e];
  }
#pragma unroll
  for (int d = 1; d < 64; d <<= 1) acc += __shfl_xor(acc, d, 64);
  if (lane == 0) out[r] = acc + w1b[0];
}

__global__ __launch_bounds__(512) void k_softmax(const float* __restrict__ s, float* __restrict__ outLog,
                                                 float* __restrict__ outAlpha) {
  __shared__ float red[8];
  int b = blockIdx.x, t = threadIdx.x;
  int lane = t & 63, wv = t >> 6;
  float v = s[b * PPn + t];
  float m = v;
#pragma unroll
  for (int d = 1; d < 64; d <<= 1) m = fmaxf(m, __shfl_xor(m, d, 64));
  if (lane == 0) red[wv] = m;
  __syncthreads();
  float mall = red[0];
#pragma unroll
  for (int i = 1; i < 8; i++) mall = fmaxf(mall, red[i]);
  __syncthreads();
  float e = __expf(v - mall);
  float sum = e;
#pragma unroll
  for (int d = 1; d < 64; d <<= 1) sum += __shfl_xor(sum, d, 64);
  if (lane == 0) red[wv] = sum;
  __syncthreads();
  float tot = red[0];
#pragma unroll
  for (int i = 1; i < 8; i++) tot += red[i];
  float lz = __logf(tot);
  outLog[b * PPn + t] = v - mall - lz;
  if (outAlpha) outAlpha[b * PPn + t] = e / tot;
}

__global__ __launch_bounds__(256) void k_c1(const float* __restrict__ alpha1, const float* __restrict__ finalF,
                                            float* __restrict__ c1) {
  __shared__ float al[512];
  int b = blockIdx.x, t = threadIdx.x;
  al[t] = alpha1[b * PPn + t];
  al[t + 256] = alpha1[b * PPn + t + 256];
  __syncthreads();
  for (int d = t; d < DD; d += 256) {
    float acc = 0.f;
#pragma unroll 8
    for (int p = 0; p < PPn; p++) acc += al[p] * finalF[((size_t)b * PPn + p) * DD + d];
    c1[b * DD + d] = acc;
  }
}

// single-step b-BiLSTM (h0=c0=0 so Whh and f-gate drop out)
__global__ __launch_bounds__(256) void k_h0a(const float* __restrict__ WTf, const float* __restrict__ WTb,
                                             const float* __restrict__ bihF, const float* __restrict__ bhhF,
                                             const float* __restrict__ bihB, const float* __restrict__ bhhB,
                                             const float* __restrict__ c1, float* __restrict__ h0a) {
  int dir = blockIdx.x >> 5, b = blockIdx.x & 31;
  const float* WT = dir ? WTb : WTf;
  const float* bih = dir ? bihB : bihF;
  const float* bhh = dir ? bhhB : bhhF;
  __shared__ float cs[DD];
  int t = threadIdx.x;
  for (int d = t; d < DD; d += 256) cs[d] = c1[b * DD + d];
  __syncthreads();
  if (t < HH) {
    float gi = bih[t] + bhh[t];
    float gg = bih[2 * HH + t] + bhh[2 * HH + t];
    float go = bih[3 * HH + t] + bhh[3 * HH + t];
    for (int d = 0; d < DD; d++) {
      float cv = cs[d];
      const float* wr2 = WT + (size_t)d * G4;
      gi = fmaf(cv, wr2[t], gi);
      gg = fmaf(cv, wr2[2 * HH + t], gg);
      go = fmaf(cv, wr2[3 * HH + t], go);
    }
    float cc = sigm(gi) * tanhfast(gg);
    h0a[b * DD + dir * HH + t] = sigm(go) * tanhfast(cc);
  }
}

__global__ __launch_bounds__(256) void k_hR(const float* __restrict__ w2a_w, const float* __restrict__ h0a,
                                            float* __restrict__ hR) {
  int b = blockIdx.x, t = threadIdx.x;
  __shared__ float hs[DD];
  for (int d = t; d < DD; d += 256) hs[d] = h0a[b * DD + d];
  __syncthreads();
  for (int e = t; e < DD; e += 256) {
    float acc = 0.f;
    const float* wr2 = w2a_w + (size_t)e * G4 + DD;   // right half of w2a_w row e
    for (int d = 0; d < DD; d++) acc = fmaf(hs[d], wr2[d], acc);
    hR[b * DD + e] = acc;
  }
}

// ---------------- launcher ----------------
extern "C" void kernel_launch(void* const* d_in, const int* in_sizes, int n_in,
                              void* d_out, int out_size, void* d_ws, size_t ws_size,
                              hipStream_t stream) {
  (void)in_sizes; (void)n_in; (void)out_size; (void)ws_size;
  const float* p_feat  = (const float*)d_in[0];
  const float* q_feat  = (const float*)d_in[1];
  const float* score_w = (const float*)d_in[2];
  const float* score_b = (const float*)d_in[3];
  const float* mWihF   = (const float*)d_in[4];
  const float* mWhhF   = (const float*)d_in[5];
  const float* mBihF   = (const float*)d_in[6];
  const float* mBhhF   = (const float*)d_in[7];
  const float* mWihB   = (const float*)d_in[8];
  const float* mWhhB   = (const float*)d_in[9];
  const float* mBihB   = (const float*)d_in[10];
  const float* mBhhB   = (const float*)d_in[11];
  const float* w2a_w   = (const float*)d_in[12];
  const float* w2a_b   = (const float*)d_in[13];
  const float* w1a_w   = (const float*)d_in[14];
  const float* w1a_b   = (const float*)d_in[15];
  const float* bWihF   = (const float*)d_in[16];
  const float* bBihF   = (const float*)d_in[18];
  const float* bBhhF   = (const float*)d_in[19];
  const float* bWihB   = (const float*)d_in[20];
  const float* bBihB   = (const float*)d_in[22];
  const float* bBhhB   = (const float*)d_in[23];

  char* ws = (char*)d_ws;
  float* XF = (float*)(ws + OFF_XF);
  float* XB = (float*)(ws + OFF_XB);
  unsigned short* FI = (unsigned short*)(ws + OFF_FI);
  float* Yv = (float*)(ws + OFF_Y);
  unsigned short* FB = (unsigned short*)(ws + OFF_FB);
  unsigned short* WFP = (unsigned short*)(ws + OFF_WFP);
  unsigned short* WBP = (unsigned short*)(ws + OFF_WBP);
  unsigned short* W2P = (unsigned short*)(ws + OFF_W2P);
  unsigned int* WPF = (unsigned int*)(ws + OFF_WPF);
  unsigned int* WPB = (unsigned int*)(ws + OFF_WPB);
  float* WTF = (float*)(ws + OFF_WTF);
  float* WTB = (float*)(ws + OFF_WTB);
  float* BIASF = (float*)(ws + OFF_BIASF);
  float* BIASB = (float*)(ws + OFF_BIASB);
  float* SP = (float*)(ws + OFF_SP);
  float* SQ = (float*)(ws + OFF_SQ);
  float* S1 = (float*)(ws + OFF_S1);
  float* AL1 = (float*)(ws + OFF_AL1);
  float* C1 = (float*)(ws + OFF_C1);
  float* H0A = (float*)(ws + OFF_H0A);
  float* HR = (float*)(ws + OFF_HR);
  float* S2 = (float*)(ws + OFF_S2);

  float* outF = (float*)d_out;
  float* outLA1 = outF + (size_t)BBn * PPn * DD;
  float* outA2 = outLA1 + (size_t)BBn * PPn;

  // prep
  k_pad_wih<<<dim3(7424, 2), 256, 0, stream>>>(mWihF, mWihB, WFP, WBP);
  k_pad_w2a<<<dim3(960), 256, 0, stream>>>(w2a_w, W2P);
  k_pack_whh<<<dim3(414, 2), 256, 0, stream>>>(mWhhF, mWhhB, WPF, WPB);
  k_pack_bwih<<<dim3(1654, 2), 256, 0, stream>>>(bWihF, bWihB, WTF, WTB);
  k_bias<<<dim3(4, 2), 256, 0, stream>>>(mBihF, mBhhF, mBihB, mBhhB, BIASF, BIASB);
  k_fbpad<<<dim3(1280), 256, 0, stream>>>(FB);
  k_rowdot<<<dim3(4096), 256, 0, stream>>>(p_feat, score_w, SP);
  k_rowdot<<<dim3(512), 256, 0, stream>>>(q_feat, score_w + DD, SQ);
  // attention -> final_in
  k_attn<<<dim3(16, 32), 256, 0, stream>>>(p_feat, q_feat, score_w, score_b, SP, SQ, FI);
  // big input-projection GEMMs
  k_gemm<<<dim3(128, 8), 256, 0, stream>>>(FI, KP1, WFP, KP1, XF, G4, G4, 58, BIASF);
  k_gemm<<<dim3(128, 8), 256, 0, stream>>>(FI, KP1, WBP, KP1, XB, G4, G4, 58, BIASB);
  // recurrence -> final (d_out) + final bf16
  k_recur<<<dim3(64), 512, 0, stream>>>(WPF, WPB, XF, XB, outF, FB);
  // ptr GEMM: Y = final @ W2aL^T + w2a_b
  k_gemm<<<dim3(128, 4), 256, 0, stream>>>(FB, KP3, W2P, KP3, Yv, DD, DD, 15, w2a_b);
  // s1 -> softmax -> c1
  k_score<<<dim3(4096), 256, 0, stream>>>(Yv, nullptr, w1a_w, w1a_b, S1);
  k_softmax<<<dim3(32), 512, 0, stream>>>(S1, outLA1, AL1);
  k_c1<<<dim3(32), 256, 0, stream>>>(AL1, outF, C1);
  // boundary BiLSTM (1 step) -> h0a -> hR
  k_h0a<<<dim3(64), 256, 0, stream>>>(WTF, WTB, bBihF, bBhhF, bBihB, bBhhB, C1, H0A);
  k_hR<<<dim3(32), 256, 0, stream>>>(w2a_w, H0A, HR);
  // s2 -> log_softmax
  k_score<<<dim3(4096), 256, 0, stream>>>(Yv, HR, w1a_w, w1a_b, S2);
  k_softmax<<<dim3(32), 512, 0, stream>>>(S2, outA2, nullptr);
}

// Round 2
// 1557.131 us; speedup vs baseline: 1.0612x; 1.0612x over previous
//
#include <hip/hip_runtime.h>

// ---------------- problem dims ----------------
#define HH 230
#define DD 460            // 2H
#define PPn 512
#define QQn 64
#define BBn 32
#define G4 920            // 4H
#define K1 1840           // 8H
#define KP1 1856          // padded K for big GEMM
#define MRn 16384         // B*P
#define KP3 480           // padded K for ptr GEMM
#define LDFB 480

typedef _Float16 f16;
typedef f16 half2v __attribute__((ext_vector_type(2)));
typedef short bf16x8_t __attribute__((ext_vector_type(8)));
typedef float f32x4_t __attribute__((ext_vector_type(4)));

// ---------------- helpers ----------------
__device__ __forceinline__ float sigm(float x) { return 1.0f / (1.0f + __expf(-x)); }
__device__ __forceinline__ float tanhfast(float x) { return 1.0f - 2.0f / (__expf(2.0f * x) + 1.0f); }

__device__ __forceinline__ unsigned short f2bf(float x) {
  unsigned int u = __builtin_bit_cast(unsigned int, x);
  unsigned int r = (u + 0x7fffu + ((u >> 16) & 1u)) >> 16;
  return (unsigned short)r;
}
__device__ __forceinline__ float bf2f(unsigned short h) {
  unsigned int u = ((unsigned int)h) << 16;
  return __builtin_bit_cast(float, u);
}

__device__ __forceinline__ float dot2f(half2v a, half2v b, float c) {
#if __has_builtin(__builtin_amdgcn_fdot2)
  return __builtin_amdgcn_fdot2(a, b, c, false);
#else
  return c + (float)a.x * (float)b.x + (float)a.y * (float)b.y;
#endif
}

// ---------------- ws layout (bytes) ----------------
static constexpr size_t SZ_X   = (size_t)MRn * G4 * 4;          // 60,293,120
static constexpr size_t OFF_XF = 0;
static constexpr size_t OFF_XB = OFF_XF + SZ_X;
static constexpr size_t OFF_FI = OFF_XB + SZ_X;                 // final_in bf16 [MR][1856]
static constexpr size_t SZ_FI  = (size_t)MRn * KP1 * 2;
static constexpr size_t OFF_Y  = OFF_FI;                         // overlay (after FI dead)
static constexpr size_t OFF_FB = OFF_FI + (size_t)MRn * DD * 4;  // overlay: final bf16 [MR][480]
static constexpr size_t OFF_WFP = OFF_FI + SZ_FI;                // [1024][1856] bf16
static constexpr size_t SZ_WP1  = (size_t)1024 * KP1 * 2;
static constexpr size_t OFF_WBP = OFF_WFP + SZ_WP1;
static constexpr size_t OFF_W2P = OFF_WBP + SZ_WP1;              // [512][480] bf16
static constexpr size_t SZ_W2P  = (size_t)512 * KP3 * 2;
static constexpr size_t OFF_WPF = OFF_W2P + SZ_W2P;              // packed Whh f16x2 [115][920]
static constexpr size_t SZ_WPK  = (size_t)115 * G4 * 4;
static constexpr size_t OFF_WPB = ((OFF_WPF + SZ_WPK + 255) & ~(size_t)255);
static constexpr size_t OFF_WTF = ((OFF_WPB + SZ_WPK + 255) & ~(size_t)255); // b_Wih^T [460][920] f32
static constexpr size_t SZ_WT   = (size_t)DD * G4 * 4;
static constexpr size_t OFF_WTB = OFF_WTF + SZ_WT;
static constexpr size_t OFF_BIASF = OFF_WTB + SZ_WT;
static constexpr size_t OFF_BIASB = ((OFF_BIASF + G4 * 4 + 255) & ~(size_t)255);
static constexpr size_t OFF_SP  = ((OFF_BIASB + G4 * 4 + 255) & ~(size_t)255); // [P*B] f32
static constexpr size_t OFF_SQ  = OFF_SP + (size_t)PPn * BBn * 4;
static constexpr size_t OFF_S1  = OFF_SQ + (size_t)QQn * BBn * 4;
static constexpr size_t OFF_AL1 = OFF_S1 + (size_t)MRn * 4;
static constexpr size_t OFF_C1  = OFF_AL1 + (size_t)MRn * 4;
static constexpr size_t OFF_H0A = ((OFF_C1 + (size_t)BBn * DD * 4 + 255) & ~(size_t)255);
static constexpr size_t OFF_HR  = ((OFF_H0A + (size_t)BBn * DD * 4 + 255) & ~(size_t)255);
static constexpr size_t OFF_S2  = ((OFF_HR + (size_t)BBn * DD * 4 + 255) & ~(size_t)255);
// total ~194.3 MB

// ---------------- prep kernels ----------------
__global__ __launch_bounds__(256) void k_pad_wih(const float* __restrict__ Wf, const float* __restrict__ Wb,
                                                 unsigned short* __restrict__ Pf, unsigned short* __restrict__ Pb) {
  size_t idx = (size_t)blockIdx.x * 256 + threadIdx.x;   // < 1024*1856
  int n = (int)(idx / KP1), k = (int)(idx % KP1);
  const float* W = blockIdx.y ? Wb : Wf;
  unsigned short* Pp = blockIdx.y ? Pb : Pf;
  float v = (n < G4 && k < K1) ? W[(size_t)n * K1 + k] : 0.f;
  Pp[idx] = f2bf(v);
}

__global__ __launch_bounds__(256) void k_pad_w2a(const float* __restrict__ W, unsigned short* __restrict__ Pq) {
  size_t idx = (size_t)blockIdx.x * 256 + threadIdx.x;   // < 512*480
  int n = (int)(idx / KP3), k = (int)(idx % KP3);
  float v = (n < DD && k < DD) ? W[(size_t)n * G4 + k] : 0.f;
  Pq[idx] = f2bf(v);
}

__global__ __launch_bounds__(256) void k_pack_whh(const float* __restrict__ Wf, const float* __restrict__ Wb,
                                                  unsigned int* __restrict__ Pf, unsigned int* __restrict__ Pb) {
  int idx = blockIdx.x * 256 + threadIdx.x;              // < 115*920
  if (idx >= 115 * G4) return;
  int kk = idx / G4, row = idx % G4;
  const float* W = blockIdx.y ? Wb : Wf;
  unsigned int* Pp = blockIdx.y ? Pb : Pf;
  half2v h; h.x = (f16)W[(size_t)row * HH + 2 * kk]; h.y = (f16)W[(size_t)row * HH + 2 * kk + 1];
  Pp[idx] = __builtin_bit_cast(unsigned int, h);
}

__global__ __launch_bounds__(256) void k_pack_bwih(const float* __restrict__ Wf, const float* __restrict__ Wb,
                                                   float* __restrict__ Tf, float* __restrict__ Tb) {
  int idx = blockIdx.x * 256 + threadIdx.x;              // < 460*920
  if (idx >= DD * G4) return;
  int d = idx / G4, row = idx % G4;
  const float* W = blockIdx.y ? Wb : Wf;
  float* T = blockIdx.y ? Tb : Tf;
  T[idx] = W[(size_t)row * DD + d];
}

__global__ __launch_bounds__(256) void k_bias(const float* __restrict__ bihF, const float* __restrict__ bhhF,
                                              const float* __restrict__ bihB, const float* __restrict__ bhhB,
                                              float* __restrict__ biasF, float* __restrict__ biasB) {
  int i = blockIdx.x * 256 + threadIdx.x;
  if (i < G4) {
    if (blockIdx.y == 0) biasF[i] = bihF[i] + bhhF[i];
    else biasB[i] = bihB[i] + bhhB[i];
  }
}

__global__ __launch_bounds__(256) void k_fbpad(unsigned short* __restrict__ FB) {
  int i = blockIdx.x * 256 + threadIdx.x;                // < 16384*20
  int r = i / 20, j = i % 20;
  FB[(size_t)r * LDFB + DD + j] = 0;
}

// sp[p*B+b] = p_features row . w   (also used for sq)
__global__ __launch_bounds__(256) void k_rowdot(const float* __restrict__ M, const float* __restrict__ w,
                                                float* __restrict__ out) {
  int r = blockIdx.x * 4 + (threadIdx.x >> 6);
  int lane = threadIdx.x & 63;
  const float* row = M + (size_t)r * DD;
  float acc = 0.f;
  for (int d = lane; d < DD; d += 64) acc += row[d] * w[d];
#pragma unroll
  for (int d = 1; d < 64; d <<= 1) acc += __shfl_xor(acc, d, 64);
  if (lane == 0) out[r] = acc;
}

// ---------------- fused attention -> final_in (bf16) ----------------
__global__ __launch_bounds__(256) void k_attn(const float* __restrict__ p_feat, const float* __restrict__ q_feat,
                                              const float* __restrict__ score_w, const float* __restrict__ score_b,
                                              const float* __restrict__ sp, const float* __restrict__ sq,
                                              unsigned short* __restrict__ FIp) {
  __shared__ half2v q_s[64 * 230];
  __shared__ half2v p_s[32 * 230];
  __shared__ half2v wpq[230];
  __shared__ float sq_s[64];
  __shared__ float u_row[64];
  __shared__ __align__(16) float w_row[64];
  __shared__ float mxs[1];

  int tid = threadIdx.x;
  int b = blockIdx.y;
  int p0 = blockIdx.x * 32;

  for (int i = tid; i < 230; i += 256) {
    half2v w; w.x = (f16)score_w[2 * DD + 2 * i]; w.y = (f16)score_w[2 * DD + 2 * i + 1];
    wpq[i] = w;
  }
  for (int i = tid; i < 64; i += 256) sq_s[i] = sq[i * BBn + b];
  for (int q = 0; q < 64; q++) {
    for (int i = tid; i < 230; i += 256) {
      float2 f2 = *(const float2*)(q_feat + ((size_t)(q * BBn + b)) * DD + 2 * i);
      half2v v; v.x = (f16)f2.x; v.y = (f16)f2.y;
      q_s[q * 230 + i] = v;
    }
  }
  for (int pl = 0; pl < 32; pl++) {
    for (int i = tid; i < 230; i += 256) {
      float2 f2 = *(const float2*)(p_feat + ((size_t)((p0 + pl) * BBn + b)) * DD + 2 * i);
      half2v v; v.x = (f16)f2.x; v.y = (f16)f2.y;
      p_s[pl * 230 + i] = v;
    }
  }
  __syncthreads();

  float sbias = score_b[0];
  int lane = tid & 63, wv = tid >> 6;
  int myq = tid >> 2, quarter = tid & 3;
  int kb = quarter * 58;
  int ke = (kb + 58 < 230) ? (kb + 58) : 230;

  for (int pl = 0; pl < 32; pl++) {
    // ---- u-dot over d for all q (4 lanes per q) ----
    float acc = 0.f;
    const half2v* prow = p_s + pl * 230;
    const half2v* qrow = q_s + myq * 230;
    for (int k = kb; k < ke; k++) {
      half2v pw = prow[k] * wpq[k];
      acc = dot2f(pw, qrow[k], acc);
    }
    acc += __shfl_xor(acc, 1, 64);
    acc += __shfl_xor(acc, 2, 64);
    if (quarter == 0) u_row[myq] = acc + sp[(p0 + pl) * BBn + b] + sq_s[myq] + sbias;
    __syncthreads();
    // ---- softmax over q (wave 0) ----
    if (wv == 0) {
      float v = u_row[lane];
      float m = v;
#pragma unroll
      for (int d = 1; d < 64; d <<= 1) m = fmaxf(m, __shfl_xor(m, d, 64));
      float e = __expf(v - m);
      float s = e;
#pragma unroll
      for (int d = 1; d < 64; d <<= 1) s += __shfl_xor(s, d, 64);
      w_row[lane] = e / s;
      if (lane == 0) mxs[0] = m;   // c2q = max_q u
    }
    __syncthreads();
    // ---- PV + write final_in ----
    if (tid < 230) {
      float c2q = mxs[0];
      half2v pv = p_s[pl * 230 + tid];
      float nux = 0.f, nuy = 0.f;
      for (int q = 0; q < 64; q += 4) {
        float4 wq = *(const float4*)&w_row[q];
        half2v q0 = q_s[(q + 0) * 230 + tid];
        half2v q1 = q_s[(q + 1) * 230 + tid];
        half2v q2 = q_s[(q + 2) * 230 + tid];
        half2v q3 = q_s[(q + 3) * 230 + tid];
        nux = fmaf(wq.x, (float)q0.x, nux); nuy = fmaf(wq.x, (float)q0.y, nuy);
        nux = fmaf(wq.y, (float)q1.x, nux); nuy = fmaf(wq.y, (float)q1.y, nuy);
        nux = fmaf(wq.z, (float)q2.x, nux); nuy = fmaf(wq.z, (float)q2.y, nuy);
        nux = fmaf(wq.w, (float)q3.x, nux); nuy = fmaf(wq.w, (float)q3.y, nuy);
      }
      float px = (float)pv.x, py = (float)pv.y;
      size_t rr = (size_t)(b * PPn + p0 + pl);
      unsigned short* o = FIp + rr * KP1 + 2 * tid;
      *(unsigned int*)(o +    0) = (unsigned int)f2bf(px)            | ((unsigned int)f2bf(py) << 16);
      *(unsigned int*)(o +  460) = (unsigned int)f2bf(c2q * px)      | ((unsigned int)f2bf(c2q * py) << 16);
      *(unsigned int*)(o +  920) = (unsigned int)f2bf(px * nux)      | ((unsigned int)f2bf(py * nuy) << 16);
      *(unsigned int*)(o + 1380) = (unsigned int)f2bf(c2q * px * px) | ((unsigned int)f2bf(c2q * py * py) << 16);
    } else if (tid < 238) {
      int j = tid - 230;
      size_t rr = (size_t)(b * PPn + p0 + pl);
      *(unsigned int*)(FIp + rr * KP1 + 1840 + 2 * j) = 0u;  // K pad
    }
    __syncthreads();
  }
}

// ---------------- bf16 MFMA GEMM: C[M][Nreal] = A[M][K] * Bw[N][K]^T (+bias) ----------------
__global__ __launch_bounds__(256, 2) void k_gemm(const unsigned short* __restrict__ A, int lda,
                                                 const unsigned short* __restrict__ Bw, int ldb,
                                                 float* __restrict__ C, int ldc,
                                                 int Nreal, int Ktiles, const float* __restrict__ bias) {
  __shared__ unsigned short As[128 * 32];
  __shared__ unsigned short Bs[128 * 32];
  int tid = threadIdx.x;
  int m0 = blockIdx.x * 128, n0 = blockIdx.y * 128;
  int wv = tid >> 6, lane = tid & 63;
  int wr = wv >> 1, wc = wv & 1;
  int laneM = lane & 15, laneK = lane >> 4;

  f32x4_t acc[4][4];
#pragma unroll
  for (int i = 0; i < 4; i++)
#pragma unroll
    for (int j = 0; j < 4; j++) acc[i][j] = (f32x4_t){0.f, 0.f, 0.f, 0.f};

  int row0 = tid >> 2, ch0 = tid & 3;
  int row1 = (256 + tid) >> 2, ch1 = tid & 3;
  const unsigned short* a0 = A + (size_t)(m0 + row0) * lda + ch0 * 8;
  const unsigned short* a1 = A + (size_t)(m0 + row1) * lda + ch1 * 8;
  const unsigned short* b0 = Bw + (size_t)(n0 + row0) * ldb + ch0 * 8;
  const unsigned short* b1 = Bw + (size_t)(n0 + row1) * ldb + ch1 * 8;

  for (int kt = 0; kt < Ktiles; kt++) {
    uint4 av0 = *(const uint4*)a0;
    uint4 av1 = *(const uint4*)a1;
    uint4 bv0 = *(const uint4*)b0;
    uint4 bv1 = *(const uint4*)b1;
    a0 += 32; a1 += 32; b0 += 32; b1 += 32;
    __syncthreads();
    *(uint4*)(As + (size_t)tid * 8)         = av0;
    *(uint4*)(As + (size_t)(256 + tid) * 8) = av1;
    *(uint4*)(Bs + (size_t)tid * 8)         = bv0;
    *(uint4*)(Bs + (size_t)(256 + tid) * 8) = bv1;
    __syncthreads();
    bf16x8_t af[4], bfr[4];
#pragma unroll
    for (int mi = 0; mi < 4; mi++)
      af[mi] = *(const bf16x8_t*)(As + (size_t)(wr * 64 + mi * 16 + laneM) * 32 + laneK * 8);
#pragma unroll
    for (int ni = 0; ni < 4; ni++)
      bfr[ni] = *(const bf16x8_t*)(Bs + (size_t)(wc * 64 + ni * 16 + laneM) * 32 + laneK * 8);
#pragma unroll
    for (int mi = 0; mi < 4; mi++)
#pragma unroll
      for (int ni = 0; ni < 4; ni++)
        acc[mi][ni] = __builtin_amdgcn_mfma_f32_16x16x32_bf16(af[mi], bfr[ni], acc[mi][ni], 0, 0, 0);
  }
#pragma unroll
  for (int mi = 0; mi < 4; mi++)
#pragma unroll
    for (int ni = 0; ni < 4; ni++) {
      int ccol = n0 + wc * 64 + ni * 16 + laneM;
      if (ccol < Nreal) {
        float bv = bias ? bias[ccol] : 0.f;
#pragma unroll
        for (int j = 0; j < 4; j++) {
          int crow = m0 + wr * 64 + mi * 16 + laneK * 4 + j;
          C[(size_t)crow * ldc + ccol] = acc[mi][ni][j] + bv;
        }
      }
    }
}

// ---------------- persistent BiLSTM recurrence ----------------
// 64 WGs: (dir, batch). Whh split: ks 0..95 in VGPRs (192 regs/thread),
// ks 96..114 in a per-thread LDS slice (10 x ds_read_b128/step, stride 44
// dwords = 11 odd b128-chunks -> bank-group (11l+j)%8 bijective, conflict-free).
// This keeps per-thread VGPR need ~225 < 256 cap (VGPR_Count=128 + scratch
// spill was the round-1 bottleneck: 4100 cyc/step instead of ~1400).
__global__ __launch_bounds__(512, 2) void k_recur(const unsigned int* __restrict__ WPf,
                                                  const unsigned int* __restrict__ WPb,
                                                  const float* __restrict__ Xf, const float* __restrict__ Xb,
                                                  float* __restrict__ outF, unsigned short* __restrict__ FB) {
  __shared__ unsigned int wlds[460 * 44];   // 80,960 B
  __shared__ unsigned int h2[2][116];
  __shared__ float abuf[232];
  int tid = threadIdx.x;
  int dir = blockIdx.x >> 5, b = blockIdx.x & 31;
  const unsigned int* __restrict__ WP = dir ? WPb : WPf;
  const float* __restrict__ X = dir ? Xb : Xf;

  bool isA = tid < 230;
  bool isB = (tid >= 256) && (tid < 486);
  bool act = isA || isB;
  int u = isA ? tid : (tid - 256);
  int row0 = isA ? u : (HH + u);                // i-row | f-row
  int row1 = isA ? (2 * HH + u) : (3 * HH + u); // g-row | o-row
  int slot = isA ? u : (230 + u);

  half2v w0[96], w1[96];
  if (act) {
#pragma unroll
    for (int k = 0; k < 96; k++) {
      w0[k] = __builtin_bit_cast(half2v, WP[k * G4 + row0]);
      w1[k] = __builtin_bit_cast(half2v, WP[k * G4 + row1]);
    }
    // LDS slice: ks 96..114 (+pad 115) interleaved (w0[k],w1[k],w0[k+1],w1[k+1])
    unsigned int* sl = &wlds[slot * 44];
#pragma unroll
    for (int j = 0; j < 10; j++) {
      int ka = 96 + 2 * j, kb2 = 97 + 2 * j;
      sl[4 * j + 0] = WP[ka * G4 + row0];
      sl[4 * j + 1] = WP[ka * G4 + row1];
      sl[4 * j + 2] = (kb2 < 115) ? WP[kb2 * G4 + row0] : 0u;
      sl[4 * j + 3] = (kb2 < 115) ? WP[kb2 * G4 + row1] : 0u;
    }
  }
  for (int i = tid; i < 116; i += 512) { h2[0][i] = 0u; h2[1][i] = 0u; }

  int col0 = u + (isB ? HH : 0);
  int col1 = col0 + 2 * HH;
  float x0 = 0.f, x1 = 0.f;
  if (act) {
    int t0 = dir ? (PPn - 1) : 0;
    const float* xr = X + (size_t)(b * PPn + t0) * G4;
    x0 = xr[col0]; x1 = xr[col1];
  }
  float c = 0.f;
  __syncthreads();

  for (int s = 0; s < PPn; s++) {
    int t = dir ? (PPn - 1 - s) : s;
    float acc0 = x0, acc1 = x1;
    if (act && s < PPn - 1) {
      int tn = dir ? (PPn - 2 - s) : (s + 1);
      const float* xr = X + (size_t)(b * PPn + tn) * G4;
      x0 = xr[col0]; x1 = xr[col1];
    }
    const unsigned int* hb = h2[s & 1];
    if (act) {
      // register part: ks 0..95
#pragma unroll
      for (int ch = 0; ch < 24; ch++) {
        uint4 hv = *(const uint4*)(hb + ch * 4);
        half2v ha = __builtin_bit_cast(half2v, hv.x);
        half2v hbv = __builtin_bit_cast(half2v, hv.y);
        half2v hc = __builtin_bit_cast(half2v, hv.z);
        half2v hd = __builtin_bit_cast(half2v, hv.w);
        acc0 = dot2f(w0[ch * 4 + 0], ha, acc0);  acc1 = dot2f(w1[ch * 4 + 0], ha, acc1);
        acc0 = dot2f(w0[ch * 4 + 1], hbv, acc0); acc1 = dot2f(w1[ch * 4 + 1], hbv, acc1);
        acc0 = dot2f(w0[ch * 4 + 2], hc, acc0);  acc1 = dot2f(w1[ch * 4 + 2], hc, acc1);
        acc0 = dot2f(w0[ch * 4 + 3], hd, acc0);  acc1 = dot2f(w1[ch * 4 + 3], hd, acc1);
      }
      // LDS-slice part: ks 96..115
      const unsigned int* sl = &wlds[slot * 44];
#pragma unroll
      for (int j = 0; j < 10; j++) {
        uint4 wv = *(const uint4*)(sl + 4 * j);
        half2v ha = __builtin_bit_cast(half2v, hb[96 + 2 * j]);
        half2v hbv = __builtin_bit_cast(half2v, hb[97 + 2 * j]);
        acc0 = dot2f(__builtin_bit_cast(half2v, wv.x), ha, acc0);
        acc1 = dot2f(__builtin_bit_cast(half2v, wv.y), ha, acc1);
        acc0 = dot2f(__builtin_bit_cast(half2v, wv.z), hbv, acc0);
        acc1 = dot2f(__builtin_bit_cast(half2v, wv.w), hbv, acc1);
      }
    }
    float ff = 0.f, oo = 0.f;
    if (isA) {
      abuf[u] = sigm(acc0) * tanhfast(acc1);   // sig(i)*tanh(g)
    }
    if (isB) { ff = sigm(acc0); oo = sigm(acc1); }
    __syncthreads();
    if (isB) {
      c = ff * c + abuf[u];
      float hval = oo * tanhfast(c);
      f16* hw = (f16*)(&h2[(s + 1) & 1][0]);
      hw[u] = (f16)hval;
      size_t ro = (size_t)(b * PPn + t);
      outF[ro * DD + dir * HH + u] = hval;
      FB[ro * LDFB + dir * HH + u] = f2bf(hval);
    }
    __syncthreads();
  }
}

// ---------------- ptr scores ----------------
__global__ __launch_bounds__(256) void k_score(const float* __restrict__ Yv, const float* __restrict__ hR,
                                               const float* __restrict__ w1a, const float* __restrict__ w1b,
                                               float* __restrict__ out) {
  int r = blockIdx.x * 4 + (threadIdx.x >> 6);
  int lane = threadIdx.x & 63;
  const float* row = Yv + (size_t)r * DD;
  const float* hrow = hR ? (hR + (size_t)(r >> 9) * DD) : nullptr;
  float acc = 0.f;
  for (int e = lane; e < DD; e += 64) {
    float v = row[e];
    if (hrow) v += hrow[e];
    acc += tanhfast(v) * w1a[e];
  }
#pragma unroll
  for (int d = 1; d < 64; d <<= 1) acc += __shfl_xor(acc, d, 64);
  if (lane == 0) out[r] = acc + w1b[0];
}

__global__ __launch_bounds__(512) void k_softmax(const float* __restrict__ s, float* __restrict__ outLog,
                                                 float* __restrict__ outAlpha) {
  __shared__ float red[8];
  int b = blockIdx.x, t = threadIdx.x;
  int lane = t & 63, wv = t >> 6;
  float v = s[b * PPn + t];
  float m = v;
#pragma unroll
  for (int d = 1; d < 64; d <<= 1) m = fmaxf(m, __shfl_xor(m, d, 64));
  if (lane == 0) red[wv] = m;
  __syncthreads();
  float mall = red[0];
#pragma unroll
  for (int i = 1; i < 8; i++) mall = fmaxf(mall, red[i]);
  __syncthreads();
  float e = __expf(v - mall);
  float sum = e;
#pragma unroll
  for (int d = 1; d < 64; d <<= 1) sum += __shfl_xor(sum, d, 64);
  if (lane == 0) red[wv] = sum;
  __syncthreads();
  float tot = red[0];
#pragma unroll
  for (int i = 1; i < 8; i++) tot += red[i];
  float lz = __logf(tot);
  outLog[b * PPn + t] = v - mall - lz;
  if (outAlpha) outAlpha[b * PPn + t] = e / tot;
}

__global__ __launch_bounds__(256) void k_c1(const float* __restrict__ alpha1, const float* __restrict__ finalF,
                                            float* __restrict__ c1) {
  __shared__ float al[512];
  int b = blockIdx.x, t = threadIdx.x;
  al[t] = alpha1[b * PPn + t];
  al[t + 256] = alpha1[b * PPn + t + 256];
  __syncthreads();
  for (int d = t; d < DD; d += 256) {
    float acc = 0.f;
#pragma unroll 8
    for (int p = 0; p < PPn; p++) acc += al[p] * finalF[((size_t)b * PPn + p) * DD + d];
    c1[b * DD + d] = acc;
  }
}

// single-step b-BiLSTM (h0=c0=0 so Whh and f-gate drop out)
__global__ __launch_bounds__(256) void k_h0a(const float* __restrict__ WTf, const float* __restrict__ WTb,
                                             const float* __restrict__ bihF, const float* __restrict__ bhhF,
                                             const float* __restrict__ bihB, const float* __restrict__ bhhB,
                                             const float* __restrict__ c1, float* __restrict__ h0a) {
  int dir = blockIdx.x >> 5, b = blockIdx.x & 31;
  const float* WT = dir ? WTb : WTf;
  const float* bih = dir ? bihB : bihF;
  const float* bhh = dir ? bhhB : bhhF;
  __shared__ float cs[DD];
  int t = threadIdx.x;
  for (int d = t; d < DD; d += 256) cs[d] = c1[b * DD + d];
  __syncthreads();
  if (t < HH) {
    float gi = bih[t] + bhh[t];
    float gg = bih[2 * HH + t] + bhh[2 * HH + t];
    float go = bih[3 * HH + t] + bhh[3 * HH + t];
    for (int d = 0; d < DD; d++) {
      float cv = cs[d];
      const float* wr2 = WT + (size_t)d * G4;
      gi = fmaf(cv, wr2[t], gi);
      gg = fmaf(cv, wr2[2 * HH + t], gg);
      go = fmaf(cv, wr2[3 * HH + t], go);
    }
    float cc = sigm(gi) * tanhfast(gg);
    h0a[b * DD + dir * HH + t] = sigm(go) * tanhfast(cc);
  }
}

__global__ __launch_bounds__(256) void k_hR(const float* __restrict__ w2a_w, const float* __restrict__ h0a,
                                            float* __restrict__ hR) {
  int b = blockIdx.x, t = threadIdx.x;
  __shared__ float hs[DD];
  for (int d = t; d < DD; d += 256) hs[d] = h0a[b * DD + d];
  __syncthreads();
  for (int e = t; e < DD; e += 256) {
    float acc = 0.f;
    const float* wr2 = w2a_w + (size_t)e * G4 + DD;   // right half of w2a_w row e
    for (int d = 0; d < DD; d++) acc = fmaf(hs[d], wr2[d], acc);
    hR[b * DD + e] = acc;
  }
}

// ---------------- launcher ----------------
extern "C" void kernel_launch(void* const* d_in, const int* in_sizes, int n_in,
                              void* d_out, int out_size, void* d_ws, size_t ws_size,
                              hipStream_t stream) {
  (void)in_sizes; (void)n_in; (void)out_size; (void)ws_size;
  const float* p_feat  = (const float*)d_in[0];
  const float* q_feat  = (const float*)d_in[1];
  const float* score_w = (const float*)d_in[2];
  const float* score_b = (const float*)d_in[3];
  const float* mWihF   = (const float*)d_in[4];
  const float* mWhhF   = (const float*)d_in[5];
  const float* mBihF   = (const float*)d_in[6];
  const float* mBhhF   = (const float*)d_in[7];
  const float* mWihB   = (const float*)d_in[8];
  const float* mWhhB   = (const float*)d_in[9];
  const float* mBihB   = (const float*)d_in[10];
  const float* mBhhB   = (const float*)d_in[11];
  const float* w2a_w   = (const float*)d_in[12];
  const float* w2a_b   = (const float*)d_in[13];
  const float* w1a_w   = (const float*)d_in[14];
  const float* w1a_b   = (const float*)d_in[15];
  const float* bWihF   = (const float*)d_in[16];
  const float* bBihF   = (const float*)d_in[18];
  const float* bBhhF   = (const float*)d_in[19];
  const float* bWihB   = (const float*)d_in[20];
  const float* bBihB   = (const float*)d_in[22];
  const float* bBhhB   = (const float*)d_in[23];

  char* ws = (char*)d_ws;
  float* XF = (float*)(ws + OFF_XF);
  float* XB = (float*)(ws + OFF_XB);
  unsigned short* FI = (unsigned short*)(ws + OFF_FI);
  float* Yv = (float*)(ws + OFF_Y);
  unsigned short* FB = (unsigned short*)(ws + OFF_FB);
  unsigned short* WFP = (unsigned short*)(ws + OFF_WFP);
  unsigned short* WBP = (unsigned short*)(ws + OFF_WBP);
  unsigned short* W2P = (unsigned short*)(ws + OFF_W2P);
  unsigned int* WPF = (unsigned int*)(ws + OFF_WPF);
  unsigned int* WPB = (unsigned int*)(ws + OFF_WPB);
  float* WTF = (float*)(ws + OFF_WTF);
  float* WTB = (float*)(ws + OFF_WTB);
  float* BIASF = (float*)(ws + OFF_BIASF);
  float* BIASB = (float*)(ws + OFF_BIASB);
  float* SP = (float*)(ws + OFF_SP);
  float* SQ = (float*)(ws + OFF_SQ);
  float* S1 = (float*)(ws + OFF_S1);
  float* AL1 = (float*)(ws + OFF_AL1);
  float* C1 = (float*)(ws + OFF_C1);
  float* H0A = (float*)(ws + OFF_H0A);
  float* HR = (float*)(ws + OFF_HR);
  float* S2 = (float*)(ws + OFF_S2);

  float* outF = (float*)d_out;
  float* outLA1 = outF + (size_t)BBn * PPn * DD;
  float* outA2 = outLA1 + (size_t)BBn * PPn;

  // prep
  k_pad_wih<<<dim3(7424, 2), 256, 0, stream>>>(mWihF, mWihB, WFP, WBP);
  k_pad_w2a<<<dim3(960), 256, 0, stream>>>(w2a_w, W2P);
  k_pack_whh<<<dim3(414, 2), 256, 0, stream>>>(mWhhF, mWhhB, WPF, WPB);
  k_pack_bwih<<<dim3(1654, 2), 256, 0, stream>>>(bWihF, bWihB, WTF, WTB);
  k_bias<<<dim3(4, 2), 256, 0, stream>>>(mBihF, mBhhF, mBihB, mBhhB, BIASF, BIASB);
  k_fbpad<<<dim3(1280), 256, 0, stream>>>(FB);
  k_rowdot<<<dim3(4096), 256, 0, stream>>>(p_feat, score_w, SP);
  k_rowdot<<<dim3(512), 256, 0, stream>>>(q_feat, score_w + DD, SQ);
  // attention -> final_in
  k_attn<<<dim3(16, 32), 256, 0, stream>>>(p_feat, q_feat, score_w, score_b, SP, SQ, FI);
  // big input-projection GEMMs
  k_gemm<<<dim3(128, 8), 256, 0, stream>>>(FI, KP1, WFP, KP1, XF, G4, G4, 58, BIASF);
  k_gemm<<<dim3(128, 8), 256, 0, stream>>>(FI, KP1, WBP, KP1, XB, G4, G4, 58, BIASB);
  // recurrence -> final (d_out) + final bf16
  k_recur<<<dim3(64), 512, 0, stream>>>(WPF, WPB, XF, XB, outF, FB);
  // ptr GEMM: Y = final @ W2aL^T + w2a_b
  k_gemm<<<dim3(128, 4), 256, 0, stream>>>(FB, KP3, W2P, KP3, Yv, DD, DD, 15, w2a_b);
  // s1 -> softmax -> c1
  k_score<<<dim3(4096), 256, 0, stream>>>(Yv, nullptr, w1a_w, w1a_b, S1);
  k_softmax<<<dim3(32), 512, 0, stream>>>(S1, outLA1, AL1);
  k_c1<<<dim3(32), 256, 0, stream>>>(AL1, outF, C1);
  // boundary BiLSTM (1 step) -> h0a -> hR
  k_h0a<<<dim3(64), 256, 0, stream>>>(WTF, WTB, bBihF, bBhhF, bBihB, bBhhB, C1, H0A);
  k_hR<<<dim3(32), 256, 0, stream>>>(w2a_w, H0A, HR);
  // s2 -> log_softmax
  k_score<<<dim3(4096), 256, 0, stream>>>(Yv, HR, w1a_w, w1a_b, S2);
  k_softmax<<<dim3(32), 512, 0, stream>>>(S2, outA2, nullptr);
}

// Round 4
// 1543.484 us; speedup vs baseline: 1.0706x; 1.0088x over previous
//
#include <hip/hip_runtime.h>

// ---------------- problem dims ----------------
#define HH 230
#define DD 460            // 2H
#define PPn 512
#define QQn 64
#define BBn 32
#define G4 920            // 4H
#define K1 1840           // 8H
#define KP1 1856          // padded K for big GEMM
#define MRn 16384         // B*P
#define KP3 480           // padded K for ptr GEMM
#define LDFB 480

typedef _Float16 f16;
typedef f16 half2v __attribute__((ext_vector_type(2)));
typedef short bf16x8_t __attribute__((ext_vector_type(8)));
typedef float f32x4_t __attribute__((ext_vector_type(4)));

// ---------------- helpers ----------------
__device__ __forceinline__ float sigm(float x) { return 1.0f / (1.0f + __expf(-x)); }
__device__ __forceinline__ float tanhfast(float x) { return 1.0f - 2.0f / (__expf(2.0f * x) + 1.0f); }

__device__ __forceinline__ unsigned short f2bf(float x) {
  unsigned int u = __builtin_bit_cast(unsigned int, x);
  unsigned int r = (u + 0x7fffu + ((u >> 16) & 1u)) >> 16;
  return (unsigned short)r;
}
__device__ __forceinline__ float bf2f(unsigned short h) {
  unsigned int u = ((unsigned int)h) << 16;
  return __builtin_bit_cast(float, u);
}

__device__ __forceinline__ float dot2f(half2v a, half2v b, float c) {
#if __has_builtin(__builtin_amdgcn_fdot2)
  return __builtin_amdgcn_fdot2(a, b, c, false);
#else
  return c + (float)a.x * (float)b.x + (float)a.y * (float)b.y;
#endif
}
__device__ __forceinline__ half2v bch2(unsigned int u) { return __builtin_bit_cast(half2v, u); }

// ---------------- ws layout (bytes) ----------------
static constexpr size_t SZ_X   = (size_t)MRn * G4 * 4;          // 60,293,120
static constexpr size_t OFF_XF = 0;
static constexpr size_t OFF_XB = OFF_XF + SZ_X;
static constexpr size_t OFF_FI = OFF_XB + SZ_X;                 // final_in bf16 [MR][1856]
static constexpr size_t SZ_FI  = (size_t)MRn * KP1 * 2;
static constexpr size_t OFF_Y  = OFF_FI;                         // overlay (after FI dead)
static constexpr size_t OFF_FB = OFF_FI + (size_t)MRn * DD * 4;  // overlay: final bf16 [MR][480]
static constexpr size_t OFF_WFP = OFF_FI + SZ_FI;                // [1024][1856] bf16
static constexpr size_t SZ_WP1  = (size_t)1024 * KP1 * 2;
static constexpr size_t OFF_WBP = OFF_WFP + SZ_WP1;
static constexpr size_t OFF_W2P = OFF_WBP + SZ_WP1;              // [512][480] bf16
static constexpr size_t SZ_W2P  = (size_t)512 * KP3 * 2;
static constexpr size_t OFF_WPF = OFF_W2P + SZ_W2P;              // packed Whh f16x2 [115][920]
static constexpr size_t SZ_WPK  = (size_t)115 * G4 * 4;
static constexpr size_t OFF_WPB = ((OFF_WPF + SZ_WPK + 255) & ~(size_t)255);
static constexpr size_t OFF_WTF = ((OFF_WPB + SZ_WPK + 255) & ~(size_t)255); // b_Wih^T [460][920] f32
static constexpr size_t SZ_WT   = (size_t)DD * G4 * 4;
static constexpr size_t OFF_WTB = OFF_WTF + SZ_WT;
static constexpr size_t OFF_BIASF = OFF_WTB + SZ_WT;
static constexpr size_t OFF_BIASB = ((OFF_BIASF + G4 * 4 + 255) & ~(size_t)255);
static constexpr size_t OFF_SP  = ((OFF_BIASB + G4 * 4 + 255) & ~(size_t)255); // [P*B] f32
static constexpr size_t OFF_SQ  = OFF_SP + (size_t)PPn * BBn * 4;
static constexpr size_t OFF_S1  = OFF_SQ + (size_t)QQn * BBn * 4;
static constexpr size_t OFF_AL1 = OFF_S1 + (size_t)MRn * 4;
static constexpr size_t OFF_C1  = OFF_AL1 + (size_t)MRn * 4;
static constexpr size_t OFF_H0A = ((OFF_C1 + (size_t)BBn * DD * 4 + 255) & ~(size_t)255);
static constexpr size_t OFF_HR  = ((OFF_H0A + (size_t)BBn * DD * 4 + 255) & ~(size_t)255);
static constexpr size_t OFF_S2  = ((OFF_HR + (size_t)BBn * DD * 4 + 255) & ~(size_t)255);
// total ~194.3 MB

// ---------------- prep kernels ----------------
__global__ __launch_bounds__(256) void k_pad_wih(const float* __restrict__ Wf, const float* __restrict__ Wb,
                                                 unsigned short* __restrict__ Pf, unsigned short* __restrict__ Pb) {
  size_t idx = (size_t)blockIdx.x * 256 + threadIdx.x;   // < 1024*1856
  int n = (int)(idx / KP1), k = (int)(idx % KP1);
  const float* W = blockIdx.y ? Wb : Wf;
  unsigned short* Pp = blockIdx.y ? Pb : Pf;
  float v = (n < G4 && k < K1) ? W[(size_t)n * K1 + k] : 0.f;
  Pp[idx] = f2bf(v);
}

__global__ __launch_bounds__(256) void k_pad_w2a(const float* __restrict__ W, unsigned short* __restrict__ Pq) {
  size_t idx = (size_t)blockIdx.x * 256 + threadIdx.x;   // < 512*480
  int n = (int)(idx / KP3), k = (int)(idx % KP3);
  float v = (n < DD && k < DD) ? W[(size_t)n * G4 + k] : 0.f;
  Pq[idx] = f2bf(v);
}

__global__ __launch_bounds__(256) void k_pack_whh(const float* __restrict__ Wf, const float* __restrict__ Wb,
                                                  unsigned int* __restrict__ Pf, unsigned int* __restrict__ Pb) {
  int idx = blockIdx.x * 256 + threadIdx.x;              // < 115*920
  if (idx >= 115 * G4) return;
  int kk = idx / G4, row = idx % G4;
  const float* W = blockIdx.y ? Wb : Wf;
  unsigned int* Pp = blockIdx.y ? Pb : Pf;
  half2v h; h.x = (f16)W[(size_t)row * HH + 2 * kk]; h.y = (f16)W[(size_t)row * HH + 2 * kk + 1];
  Pp[idx] = __builtin_bit_cast(unsigned int, h);
}

__global__ __launch_bounds__(256) void k_pack_bwih(const float* __restrict__ Wf, const float* __restrict__ Wb,
                                                   float* __restrict__ Tf, float* __restrict__ Tb) {
  int idx = blockIdx.x * 256 + threadIdx.x;              // < 460*920
  if (idx >= DD * G4) return;
  int d = idx / G4, row = idx % G4;
  const float* W = blockIdx.y ? Wb : Wf;
  float* T = blockIdx.y ? Tb : Tf;
  T[idx] = W[(size_t)row * DD + d];
}

__global__ __launch_bounds__(256) void k_bias(const float* __restrict__ bihF, const float* __restrict__ bhhF,
                                              const float* __restrict__ bihB, const float* __restrict__ bhhB,
                                              float* __restrict__ biasF, float* __restrict__ biasB) {
  int i = blockIdx.x * 256 + threadIdx.x;
  if (i < G4) {
    if (blockIdx.y == 0) biasF[i] = bihF[i] + bhhF[i];
    else biasB[i] = bihB[i] + bhhB[i];
  }
}

__global__ __launch_bounds__(256) void k_fbpad(unsigned short* __restrict__ FB) {
  int i = blockIdx.x * 256 + threadIdx.x;                // < 16384*20
  int r = i / 20, j = i % 20;
  FB[(size_t)r * LDFB + DD + j] = 0;
}

// sp[p*B+b] = p_features row . w   (also used for sq)
__global__ __launch_bounds__(256) void k_rowdot(const float* __restrict__ M, const float* __restrict__ w,
                                                float* __restrict__ out) {
  int r = blockIdx.x * 4 + (threadIdx.x >> 6);
  int lane = threadIdx.x & 63;
  const float* row = M + (size_t)r * DD;
  float acc = 0.f;
  for (int d = lane; d < DD; d += 64) acc += row[d] * w[d];
#pragma unroll
  for (int d = 1; d < 64; d <<= 1) acc += __shfl_xor(acc, d, 64);
  if (lane == 0) out[r] = acc;
}

// ---------------- fused attention -> final_in (bf16) ----------------
__global__ __launch_bounds__(256) void k_attn(const float* __restrict__ p_feat, const float* __restrict__ q_feat,
                                              const float* __restrict__ score_w, const float* __restrict__ score_b,
                                              const float* __restrict__ sp, const float* __restrict__ sq,
                                              unsigned short* __restrict__ FIp) {
  __shared__ half2v q_s[64 * 230];
  __shared__ half2v p_s[32 * 230];
  __shared__ half2v wpq[230];
  __shared__ float sq_s[64];
  __shared__ float u_row[64];
  __shared__ __align__(16) float w_row[64];
  __shared__ float mxs[1];

  int tid = threadIdx.x;
  int b = blockIdx.y;
  int p0 = blockIdx.x * 32;

  for (int i = tid; i < 230; i += 256) {
    half2v w; w.x = (f16)score_w[2 * DD + 2 * i]; w.y = (f16)score_w[2 * DD + 2 * i + 1];
    wpq[i] = w;
  }
  for (int i = tid; i < 64; i += 256) sq_s[i] = sq[i * BBn + b];
  for (int q = 0; q < 64; q++) {
    for (int i = tid; i < 230; i += 256) {
      float2 f2 = *(const float2*)(q_feat + ((size_t)(q * BBn + b)) * DD + 2 * i);
      half2v v; v.x = (f16)f2.x; v.y = (f16)f2.y;
      q_s[q * 230 + i] = v;
    }
  }
  for (int pl = 0; pl < 32; pl++) {
    for (int i = tid; i < 230; i += 256) {
      float2 f2 = *(const float2*)(p_feat + ((size_t)((p0 + pl) * BBn + b)) * DD + 2 * i);
      half2v v; v.x = (f16)f2.x; v.y = (f16)f2.y;
      p_s[pl * 230 + i] = v;
    }
  }
  __syncthreads();

  float sbias = score_b[0];
  int lane = tid & 63, wv = tid >> 6;
  int myq = tid >> 2, quarter = tid & 3;
  int kb = quarter * 58;
  int ke = (kb + 58 < 230) ? (kb + 58) : 230;

  for (int pl = 0; pl < 32; pl++) {
    // ---- u-dot over d for all q (4 lanes per q) ----
    float acc = 0.f;
    const half2v* prow = p_s + pl * 230;
    const half2v* qrow = q_s + myq * 230;
    for (int k = kb; k < ke; k++) {
      half2v pw = prow[k] * wpq[k];
      acc = dot2f(pw, qrow[k], acc);
    }
    acc += __shfl_xor(acc, 1, 64);
    acc += __shfl_xor(acc, 2, 64);
    if (quarter == 0) u_row[myq] = acc + sp[(p0 + pl) * BBn + b] + sq_s[myq] + sbias;
    __syncthreads();
    // ---- softmax over q (wave 0) ----
    if (wv == 0) {
      float v = u_row[lane];
      float m = v;
#pragma unroll
      for (int d = 1; d < 64; d <<= 1) m = fmaxf(m, __shfl_xor(m, d, 64));
      float e = __expf(v - m);
      float s = e;
#pragma unroll
      for (int d = 1; d < 64; d <<= 1) s += __shfl_xor(s, d, 64);
      w_row[lane] = e / s;
      if (lane == 0) mxs[0] = m;   // c2q = max_q u
    }
    __syncthreads();
    // ---- PV + write final_in ----
    if (tid < 230) {
      float c2q = mxs[0];
      half2v pv = p_s[pl * 230 + tid];
      float nux = 0.f, nuy = 0.f;
      for (int q = 0; q < 64; q += 4) {
        float4 wq = *(const float4*)&w_row[q];
        half2v q0 = q_s[(q + 0) * 230 + tid];
        half2v q1 = q_s[(q + 1) * 230 + tid];
        half2v q2 = q_s[(q + 2) * 230 + tid];
        half2v q3 = q_s[(q + 3) * 230 + tid];
        nux = fmaf(wq.x, (float)q0.x, nux); nuy = fmaf(wq.x, (float)q0.y, nuy);
        nux = fmaf(wq.y, (float)q1.x, nux); nuy = fmaf(wq.y, (float)q1.y, nuy);
        nux = fmaf(wq.z, (float)q2.x, nux); nuy = fmaf(wq.z, (float)q2.y, nuy);
        nux = fmaf(wq.w, (float)q3.x, nux); nuy = fmaf(wq.w, (float)q3.y, nuy);
      }
      float px = (float)pv.x, py = (float)pv.y;
      size_t rr = (size_t)(b * PPn + p0 + pl);
      unsigned short* o = FIp + rr * KP1 + 2 * tid;
      *(unsigned int*)(o +    0) = (unsigned int)f2bf(px)            | ((unsigned int)f2bf(py) << 16);
      *(unsigned int*)(o +  460) = (unsigned int)f2bf(c2q * px)      | ((unsigned int)f2bf(c2q * py) << 16);
      *(unsigned int*)(o +  920) = (unsigned int)f2bf(px * nux)      | ((unsigned int)f2bf(py * nuy) << 16);
      *(unsigned int*)(o + 1380) = (unsigned int)f2bf(c2q * px * px) | ((unsigned int)f2bf(c2q * py * py) << 16);
    } else if (tid < 238) {
      int j = tid - 230;
      size_t rr = (size_t)(b * PPn + p0 + pl);
      *(unsigned int*)(FIp + rr * KP1 + 1840 + 2 * j) = 0u;  // K pad
    }
    __syncthreads();
  }
}

// ---------------- bf16 MFMA GEMM: C[M][Nreal] = A[M][K] * Bw[N][K]^T (+bias) ----------------
__global__ __launch_bounds__(256, 2) void k_gemm(const unsigned short* __restrict__ A, int lda,
                                                 const unsigned short* __restrict__ Bw, int ldb,
                                                 float* __restrict__ C, int ldc,
                                                 int Nreal, int Ktiles, const float* __restrict__ bias) {
  __shared__ unsigned short As[128 * 32];
  __shared__ unsigned short Bs[128 * 32];
  int tid = threadIdx.x;
  int m0 = blockIdx.x * 128, n0 = blockIdx.y * 128;
  int wv = tid >> 6, lane = tid & 63;
  int wr = wv >> 1, wc = wv & 1;
  int laneM = lane & 15, laneK = lane >> 4;

  f32x4_t acc[4][4];
#pragma unroll
  for (int i = 0; i < 4; i++)
#pragma unroll
    for (int j = 0; j < 4; j++) acc[i][j] = (f32x4_t){0.f, 0.f, 0.f, 0.f};

  int row0 = tid >> 2, ch0 = tid & 3;
  int row1 = (256 + tid) >> 2, ch1 = tid & 3;
  const unsigned short* a0 = A + (size_t)(m0 + row0) * lda + ch0 * 8;
  const unsigned short* a1 = A + (size_t)(m0 + row1) * lda + ch1 * 8;
  const unsigned short* b0 = Bw + (size_t)(n0 + row0) * ldb + ch0 * 8;
  const unsigned short* b1 = Bw + (size_t)(n0 + row1) * ldb + ch1 * 8;

  for (int kt = 0; kt < Ktiles; kt++) {
    uint4 av0 = *(const uint4*)a0;
    uint4 av1 = *(const uint4*)a1;
    uint4 bv0 = *(const uint4*)b0;
    uint4 bv1 = *(const uint4*)b1;
    a0 += 32; a1 += 32; b0 += 32; b1 += 32;
    __syncthreads();
    *(uint4*)(As + (size_t)tid * 8)         = av0;
    *(uint4*)(As + (size_t)(256 + tid) * 8) = av1;
    *(uint4*)(Bs + (size_t)tid * 8)         = bv0;
    *(uint4*)(Bs + (size_t)(256 + tid) * 8) = bv1;
    __syncthreads();
    bf16x8_t af[4], bfr[4];
#pragma unroll
    for (int mi = 0; mi < 4; mi++)
      af[mi] = *(const bf16x8_t*)(As + (size_t)(wr * 64 + mi * 16 + laneM) * 32 + laneK * 8);
#pragma unroll
    for (int ni = 0; ni < 4; ni++)
      bfr[ni] = *(const bf16x8_t*)(Bs + (size_t)(wc * 64 + ni * 16 + laneM) * 32 + laneK * 8);
#pragma unroll
    for (int mi = 0; mi < 4; mi++)
#pragma unroll
      for (int ni = 0; ni < 4; ni++)
        acc[mi][ni] = __builtin_amdgcn_mfma_f32_16x16x32_bf16(af[mi], bfr[ni], acc[mi][ni], 0, 0, 0);
  }
#pragma unroll
  for (int mi = 0; mi < 4; mi++)
#pragma unroll
    for (int ni = 0; ni < 4; ni++) {
      int ccol = n0 + wc * 64 + ni * 16 + laneM;
      if (ccol < Nreal) {
        float bv = bias ? bias[ccol] : 0.f;
#pragma unroll
        for (int j = 0; j < 4; j++) {
          int crow = m0 + wr * 64 + mi * 16 + laneK * 4 + j;
          C[(size_t)crow * ldc + ccol] = acc[mi][ni][j] + bv;
        }
      }
    }
}

// ---------------- persistent BiLSTM recurrence ----------------
// 64 WGs: (dir, batch). Whh split: ks 0..103 in VGPRs (208 regs/thread),
// ks 104..114 (+zero pad 115) in per-thread LDS slices (6 ds_read_b128/step,
// chunk stride 7 -> bank-group (7l+j)%8 bijective, conflict-free).
// R1/R2 post-mortem: __launch_bounds__(512,2) yielded a 128-VGPR budget
// (2nd arg acts like blocks/CU: 16 waves/CU -> 512/4=128) and the weight
// array spilled (cost ~5us per spilled k-pair, verified by the R2 delta).
// Explicit amdgpu_waves_per_eu(1,2) + exact flat_work_group_size pins the
// budget at 256; demand ~240.
__global__ __attribute__((amdgpu_flat_work_group_size(512, 512)))
__attribute__((amdgpu_waves_per_eu(1, 2)))
void k_recur(const unsigned int* __restrict__ WPf,
             const unsigned int* __restrict__ WPb,
             const float* __restrict__ Xf, const float* __restrict__ Xb,
             float* __restrict__ outF, unsigned short* __restrict__ FB) {
  __shared__ unsigned int wlds[460 * 28];   // 51,520 B
  __shared__ unsigned int h2[2][116];
  __shared__ float abuf[232];
  int tid = threadIdx.x;
  int dir = blockIdx.x >> 5, b = blockIdx.x & 31;
  const unsigned int* __restrict__ WP = dir ? WPb : WPf;
  const float* __restrict__ X = dir ? Xb : Xf;

  bool isA = tid < 230;
  bool isB = (tid >= 256) && (tid < 486);
  bool act = isA || isB;
  int u = isA ? tid : (tid - 256);
  int row0 = isA ? u : (HH + u);                // i-row | f-row
  int row1 = isA ? (2 * HH + u) : (3 * HH + u); // g-row | o-row
  int slot = isA ? u : (230 + u);

  half2v w0[104], w1[104];
  if (act) {
#pragma unroll
    for (int k = 0; k < 104; k++) {
      w0[k] = bch2(WP[k * G4 + row0]);
      w1[k] = bch2(WP[k * G4 + row1]);
    }
    // LDS slice: ks 104..114 (+pad 115) interleaved (w0[ka],w1[ka],w0[kb],w1[kb])
    unsigned int* sl = &wlds[slot * 28];
#pragma unroll
    for (int j = 0; j < 6; j++) {
      int ka = 104 + 2 * j, kb2 = 105 + 2 * j;
      sl[4 * j + 0] = WP[ka * G4 + row0];
      sl[4 * j + 1] = WP[ka * G4 + row1];
      sl[4 * j + 2] = (kb2 < 115) ? WP[kb2 * G4 + row0] : 0u;
      sl[4 * j + 3] = (kb2 < 115) ? WP[kb2 * G4 + row1] : 0u;
    }
  }
  for (int i = tid; i < 116; i += 512) { h2[0][i] = 0u; h2[1][i] = 0u; }

  int col0 = u + (isB ? HH : 0);
  int col1 = col0 + 2 * HH;
  float x0 = 0.f, x1 = 0.f;
  if (act) {
    int t0 = dir ? (PPn - 1) : 0;
    const float* xr = X + (size_t)(b * PPn + t0) * G4;
    x0 = xr[col0]; x1 = xr[col1];
  }
  float c = 0.f;
  __syncthreads();

  for (int s = 0; s < PPn; s++) {
    int t = dir ? (PPn - 1 - s) : s;
    float acc0 = x0, acc1 = x1;
    if (act && s < PPn - 1) {
      int tn = dir ? (PPn - 2 - s) : (s + 1);
      const float* xr = X + (size_t)(b * PPn + tn) * G4;
      x0 = xr[col0]; x1 = xr[col1];
    }
    const unsigned int* hb = h2[s & 1];
    if (act) {
      // register part: ks 0..103
#pragma unroll
      for (int ch = 0; ch < 26; ch++) {
        uint4 hv = *(const uint4*)(hb + ch * 4);
        half2v ha = bch2(hv.x);
        half2v hbv = bch2(hv.y);
        half2v hc = bch2(hv.z);
        half2v hd = bch2(hv.w);
        acc0 = dot2f(w0[ch * 4 + 0], ha, acc0);  acc1 = dot2f(w1[ch * 4 + 0], ha, acc1);
        acc0 = dot2f(w0[ch * 4 + 1], hbv, acc0); acc1 = dot2f(w1[ch * 4 + 1], hbv, acc1);
        acc0 = dot2f(w0[ch * 4 + 2], hc, acc0);  acc1 = dot2f(w1[ch * 4 + 2], hc, acc1);
        acc0 = dot2f(w0[ch * 4 + 3], hd, acc0);  acc1 = dot2f(w1[ch * 4 + 3], hd, acc1);
      }
      // LDS-slice part: ks 104..115 (k=115 weight is zero)
      const unsigned int* sl = &wlds[slot * 28];
#pragma unroll
      for (int j = 0; j < 3; j++) {
        uint4 wva = *(const uint4*)(sl + 8 * j);
        uint4 wvb = *(const uint4*)(sl + 8 * j + 4);
        uint4 hv = *(const uint4*)(hb + 104 + 4 * j);
        half2v ha = bch2(hv.x);
        half2v hbv = bch2(hv.y);
        half2v hc = bch2(hv.z);
        half2v hd = bch2(hv.w);
        acc0 = dot2f(bch2(wva.x), ha, acc0);  acc1 = dot2f(bch2(wva.y), ha, acc1);
        acc0 = dot2f(bch2(wva.z), hbv, acc0); acc1 = dot2f(bch2(wva.w), hbv, acc1);
        acc0 = dot2f(bch2(wvb.x), hc, acc0);  acc1 = dot2f(bch2(wvb.y), hc, acc1);
        acc0 = dot2f(bch2(wvb.z), hd, acc0);  acc1 = dot2f(bch2(wvb.w), hd, acc1);
      }
    }
    float ff = 0.f, oo = 0.f;
    if (isA) {
      abuf[u] = sigm(acc0) * tanhfast(acc1);   // sig(i)*tanh(g)
    }
    if (isB) { ff = sigm(acc0); oo = sigm(acc1); }
    __syncthreads();
    if (isB) {
      c = ff * c + abuf[u];
      float hval = oo * tanhfast(c);
      f16* hw = (f16*)(&h2[(s + 1) & 1][0]);
      hw[u] = (f16)hval;
      size_t ro = (size_t)(b * PPn + t);
      outF[ro * DD + dir * HH + u] = hval;
      FB[ro * LDFB + dir * HH + u] = f2bf(hval);
    }
    __syncthreads();
  }
}

// ---------------- ptr scores ----------------
__global__ __launch_bounds__(256) void k_score(const float* __restrict__ Yv, const float* __restrict__ hR,
                                               const float* __restrict__ w1a, const float* __restrict__ w1b,
                                               float* __restrict__ out) {
  int r = blockIdx.x * 4 + (threadIdx.x >> 6);
  int lane = threadIdx.x & 63;
  const float* row = Yv + (size_t)r * DD;
  const float* hrow = hR ? (hR + (size_t)(r >> 9) * DD) : nullptr;
  float acc = 0.f;
  for (int e = lane; e < DD; e += 64) {
    float v = row[e];
    if (hrow) v += hrow[e];
    acc += tanhfast(v) * w1a[e];
  }
#pragma unroll
  for (int d = 1; d < 64; d <<= 1) acc += __shfl_xor(acc, d, 64);
  if (lane == 0) out[r] = acc + w1b[0];
}

__global__ __launch_bounds__(512) void k_softmax(const float* __restrict__ s, float* __restrict__ outLog,
                                                 float* __restrict__ outAlpha) {
  __shared__ float red[8];
  int b = blockIdx.x, t = threadIdx.x;
  int lane = t & 63, wv = t >> 6;
  float v = s[b * PPn + t];
  float m = v;
#pragma unroll
  for (int d = 1; d < 64; d <<= 1) m = fmaxf(m, __shfl_xor(m, d, 64));
  if (lane == 0) red[wv] = m;
  __syncthreads();
  float mall = red[0];
#pragma unroll
  for (int i = 1; i < 8; i++) mall = fmaxf(mall, red[i]);
  __syncthreads();
  float e = __expf(v - mall);
  float sum = e;
#pragma unroll
  for (int d = 1; d < 64; d <<= 1) sum += __shfl_xor(sum, d, 64);
  if (lane == 0) red[wv] = sum;
  __syncthreads();
  float tot = red[0];
#pragma unroll
  for (int i = 1; i < 8; i++) tot += red[i];
  float lz = __logf(tot);
  outLog[b * PPn + t] = v - mall - lz;
  if (outAlpha) outAlpha[b * PPn + t] = e / tot;
}

__global__ __launch_bounds__(256) void k_c1(const float* __restrict__ alpha1, const float* __restrict__ finalF,
                                            float* __restrict__ c1) {
  __shared__ float al[512];
  int b = blockIdx.x, t = threadIdx.x;
  al[t] = alpha1[b * PPn + t];
  al[t + 256] = alpha1[b * PPn + t + 256];
  __syncthreads();
  for (int d = t; d < DD; d += 256) {
    float acc = 0.f;
#pragma unroll 8
    for (int p = 0; p < PPn; p++) acc += al[p] * finalF[((size_t)b * PPn + p) * DD + d];
    c1[b * DD + d] = acc;
  }
}

// single-step b-BiLSTM (h0=c0=0 so Whh and f-gate drop out)
__global__ __launch_bounds__(256) void k_h0a(const float* __restrict__ WTf, const float* __restrict__ WTb,
                                             const float* __restrict__ bihF, const float* __restrict__ bhhF,
                                             const float* __restrict__ bihB, const float* __restrict__ bhhB,
                                             const float* __restrict__ c1, float* __restrict__ h0a) {
  int dir = blockIdx.x >> 5, b = blockIdx.x & 31;
  const float* WT = dir ? WTb : WTf;
  const float* bih = dir ? bihB : bihF;
  const float* bhh = dir ? bhhB : bhhF;
  __shared__ float cs[DD];
  int t = threadIdx.x;
  for (int d = t; d < DD; d += 256) cs[d] = c1[b * DD + d];
  __syncthreads();
  if (t < HH) {
    float gi = bih[t] + bhh[t];
    float gg = bih[2 * HH + t] + bhh[2 * HH + t];
    float go = bih[3 * HH + t] + bhh[3 * HH + t];
    for (int d = 0; d < DD; d++) {
      float cv = cs[d];
      const float* wr2 = WT + (size_t)d * G4;
      gi = fmaf(cv, wr2[t], gi);
      gg = fmaf(cv, wr2[2 * HH + t], gg);
      go = fmaf(cv, wr2[3 * HH + t], go);
    }
    float cc = sigm(gi) * tanhfast(gg);
    h0a[b * DD + dir * HH + t] = sigm(go) * tanhfast(cc);
  }
}

__global__ __launch_bounds__(256) void k_hR(const float* __restrict__ w2a_w, const float* __restrict__ h0a,
                                            float* __restrict__ hR) {
  int b = blockIdx.x, t = threadIdx.x;
  __shared__ float hs[DD];
  for (int d = t; d < DD; d += 256) hs[d] = h0a[b * DD + d];
  __syncthreads();
  for (int e = t; e < DD; e += 256) {
    float acc = 0.f;
    const float* wr2 = w2a_w + (size_t)e * G4 + DD;   // right half of w2a_w row e
    for (int d = 0; d < DD; d++) acc = fmaf(hs[d], wr2[d], acc);
    hR[b * DD + e] = acc;
  }
}

// ---------------- launcher ----------------
extern "C" void kernel_launch(void* const* d_in, const int* in_sizes, int n_in,
                              void* d_out, int out_size, void* d_ws, size_t ws_size,
                              hipStream_t stream) {
  (void)in_sizes; (void)n_in; (void)out_size; (void)ws_size;
  const float* p_feat  = (const float*)d_in[0];
  const float* q_feat  = (const float*)d_in[1];
  const float* score_w = (const float*)d_in[2];
  const float* score_b = (const float*)d_in[3];
  const float* mWihF   = (const float*)d_in[4];
  const float* mWhhF   = (const float*)d_in[5];
  const float* mBihF   = (const float*)d_in[6];
  const float* mBhhF   = (const float*)d_in[7];
  const float* mWihB   = (const float*)d_in[8];
  const float* mWhhB   = (const float*)d_in[9];
  const float* mBihB   = (const float*)d_in[10];
  const float* mBhhB   = (const float*)d_in[11];
  const float* w2a_w   = (const float*)d_in[12];
  const float* w2a_b   = (const float*)d_in[13];
  const float* w1a_w   = (const float*)d_in[14];
  const float* w1a_b   = (const float*)d_in[15];
  const float* bWihF   = (const float*)d_in[16];
  const float* bBihF   = (const float*)d_in[18];
  const float* bBhhF   = (const float*)d_in[19];
  const float* bWihB   = (const float*)d_in[20];
  const float* bBihB   = (const float*)d_in[22];
  const float* bBhhB   = (const float*)d_in[23];

  char* ws = (char*)d_ws;
  float* XF = (float*)(ws + OFF_XF);
  float* XB = (float*)(ws + OFF_XB);
  unsigned short* FI = (unsigned short*)(ws + OFF_FI);
  float* Yv = (float*)(ws + OFF_Y);
  unsigned short* FB = (unsigned short*)(ws + OFF_FB);
  unsigned short* WFP = (unsigned short*)(ws + OFF_WFP);
  unsigned short* WBP = (unsigned short*)(ws + OFF_WBP);
  unsigned short* W2P = (unsigned short*)(ws + OFF_W2P);
  unsigned int* WPF = (unsigned int*)(ws + OFF_WPF);
  unsigned int* WPB = (unsigned int*)(ws + OFF_WPB);
  float* WTF = (float*)(ws + OFF_WTF);
  float* WTB = (float*)(ws + OFF_WTB);
  float* BIASF = (float*)(ws + OFF_BIASF);
  float* BIASB = (float*)(ws + OFF_BIASB);
  float* SP = (float*)(ws + OFF_SP);
  float* SQ = (float*)(ws + OFF_SQ);
  float* S1 = (float*)(ws + OFF_S1);
  float* AL1 = (float*)(ws + OFF_AL1);
  float* C1 = (float*)(ws + OFF_C1);
  float* H0A = (float*)(ws + OFF_H0A);
  float* HR = (float*)(ws + OFF_HR);
  float* S2 = (float*)(ws + OFF_S2);

  float* outF = (float*)d_out;
  float* outLA1 = outF + (size_t)BBn * PPn * DD;
  float* outA2 = outLA1 + (size_t)BBn * PPn;

  // prep
  k_pad_wih<<<dim3(7424, 2), 256, 0, stream>>>(mWihF, mWihB, WFP, WBP);
  k_pad_w2a<<<dim3(960), 256, 0, stream>>>(w2a_w, W2P);
  k_pack_whh<<<dim3(414, 2), 256, 0, stream>>>(mWhhF, mWhhB, WPF, WPB);
  k_pack_bwih<<<dim3(1654, 2), 256, 0, stream>>>(bWihF, bWihB, WTF, WTB);
  k_bias<<<dim3(4, 2), 256, 0, stream>>>(mBihF, mBhhF, mBihB, mBhhB, BIASF, BIASB);
  k_fbpad<<<dim3(1280), 256, 0, stream>>>(FB);
  k_rowdot<<<dim3(4096), 256, 0, stream>>>(p_feat, score_w, SP);
  k_rowdot<<<dim3(512), 256, 0, stream>>>(q_feat, score_w + DD, SQ);
  // attention -> final_in
  k_attn<<<dim3(16, 32), 256, 0, stream>>>(p_feat, q_feat, score_w, score_b, SP, SQ, FI);
  // big input-projection GEMMs
  k_gemm<<<dim3(128, 8), 256, 0, stream>>>(FI, KP1, WFP, KP1, XF, G4, G4, 58, BIASF);
  k_gemm<<<dim3(128, 8), 256, 0, stream>>>(FI, KP1, WBP, KP1, XB, G4, G4, 58, BIASB);
  // recurrence -> final (d_out) + final bf16
  k_recur<<<dim3(64), 512, 0, stream>>>(WPF, WPB, XF, XB, outF, FB);
  // ptr GEMM: Y = final @ W2aL^T + w2a_b
  k_gemm<<<dim3(128, 4), 256, 0, stream>>>(FB, KP3, W2P, KP3, Yv, DD, DD, 15, w2a_b);
  // s1 -> softmax -> c1
  k_score<<<dim3(4096), 256, 0, stream>>>(Yv, nullptr, w1a_w, w1a_b, S1);
  k_softmax<<<dim3(32), 512, 0, stream>>>(S1, outLA1, AL1);
  k_c1<<<dim3(32), 256, 0, stream>>>(AL1, outF, C1);
  // boundary BiLSTM (1 step) -> h0a -> hR
  k_h0a<<<dim3(64), 256, 0, stream>>>(WTF, WTB, bBihF, bBhhF, bBihB, bBhhB, C1, H0A);
  k_hR<<<dim3(32), 256, 0, stream>>>(w2a_w, H0A, HR);
  // s2 -> log_softmax
  k_score<<<dim3(4096), 256, 0, stream>>>(Yv, HR, w1a_w, w1a_b, S2);
  k_softmax<<<dim3(32), 512, 0, stream>>>(S2, outA2, nullptr);
}

// Round 6
// 1533.901 us; speedup vs baseline: 1.0773x; 1.0062x over previous
//
#include <hip/hip_runtime.h>

// ---------------- problem dims ----------------
#define HH 230
#define DD 460            // 2H
#define PPn 512
#define QQn 64
#define BBn 32
#define G4 920            // 4H
#define K1 1840           // 8H
#define KP1 1856          // padded K for big GEMM
#define MRn 16384         // B*P
#define KP3 480           // padded K for ptr GEMM
#define LDFB 480

typedef _Float16 f16;
typedef f16 half2v __attribute__((ext_vector_type(2)));
typedef short bf16x8_t __attribute__((ext_vector_type(8)));
typedef float f32x4_t __attribute__((ext_vector_type(4)));

// ---------------- helpers ----------------
__device__ __forceinline__ float sigm(float x) { return 1.0f / (1.0f + __expf(-x)); }
__device__ __forceinline__ float tanhfast(float x) { return 1.0f - 2.0f / (__expf(2.0f * x) + 1.0f); }

__device__ __forceinline__ unsigned short f2bf(float x) {
  unsigned int u = __builtin_bit_cast(unsigned int, x);
  unsigned int r = (u + 0x7fffu + ((u >> 16) & 1u)) >> 16;
  return (unsigned short)r;
}
__device__ __forceinline__ float bf2f(unsigned short h) {
  unsigned int u = ((unsigned int)h) << 16;
  return __builtin_bit_cast(float, u);
}

__device__ __forceinline__ float dot2f(half2v a, half2v b, float c) {
#if __has_builtin(__builtin_amdgcn_fdot2)
  return __builtin_amdgcn_fdot2(a, b, c, false);
#else
  return c + (float)a.x * (float)b.x + (float)a.y * (float)b.y;
#endif
}
__device__ __forceinline__ half2v bch2(unsigned int u) { return __builtin_bit_cast(half2v, u); }

// ---------------- ws layout (bytes) ----------------
static constexpr size_t SZ_X   = (size_t)MRn * G4 * 4;          // 60,293,120
static constexpr size_t OFF_XF = 0;
static constexpr size_t OFF_XB = OFF_XF + SZ_X;
static constexpr size_t OFF_FI = OFF_XB + SZ_X;                 // final_in bf16 [MR][1856]
static constexpr size_t SZ_FI  = (size_t)MRn * KP1 * 2;
static constexpr size_t OFF_Y  = OFF_FI;                         // overlay (after FI dead)
static constexpr size_t OFF_FB = OFF_FI + (size_t)MRn * DD * 4;  // overlay: final bf16 [MR][480]
static constexpr size_t OFF_WFP = OFF_FI + SZ_FI;                // [1024][1856] bf16
static constexpr size_t SZ_WP1  = (size_t)1024 * KP1 * 2;
static constexpr size_t OFF_WBP = OFF_WFP + SZ_WP1;
static constexpr size_t OFF_W2P = OFF_WBP + SZ_WP1;              // [512][480] bf16
static constexpr size_t SZ_W2P  = (size_t)512 * KP3 * 2;
static constexpr size_t OFF_WPF = OFF_W2P + SZ_W2P;              // packed Whh f16x2 [115][920]
static constexpr size_t SZ_WPK  = (size_t)115 * G4 * 4;
static constexpr size_t OFF_WPB = ((OFF_WPF + SZ_WPK + 255) & ~(size_t)255);
static constexpr size_t OFF_WTF = ((OFF_WPB + SZ_WPK + 255) & ~(size_t)255); // b_Wih^T [460][920] f32
static constexpr size_t SZ_WT   = (size_t)DD * G4 * 4;
static constexpr size_t OFF_WTB = OFF_WTF + SZ_WT;
static constexpr size_t OFF_BIASF = OFF_WTB + SZ_WT;
static constexpr size_t OFF_BIASB = ((OFF_BIASF + G4 * 4 + 255) & ~(size_t)255);
static constexpr size_t OFF_SP  = ((OFF_BIASB + G4 * 4 + 255) & ~(size_t)255); // [P*B] f32
static constexpr size_t OFF_SQ  = OFF_SP + (size_t)PPn * BBn * 4;
static constexpr size_t OFF_S1  = OFF_SQ + (size_t)QQn * BBn * 4;
static constexpr size_t OFF_AL1 = OFF_S1 + (size_t)MRn * 4;
static constexpr size_t OFF_C1  = OFF_AL1 + (size_t)MRn * 4;
static constexpr size_t OFF_H0A = ((OFF_C1 + (size_t)BBn * DD * 4 + 255) & ~(size_t)255);
static constexpr size_t OFF_HR  = ((OFF_H0A + (size_t)BBn * DD * 4 + 255) & ~(size_t)255);
static constexpr size_t OFF_S2  = ((OFF_HR + (size_t)BBn * DD * 4 + 255) & ~(size_t)255);
// total ~194.3 MB

// ---------------- prep kernels ----------------
__global__ __launch_bounds__(256) void k_pad_wih(const float* __restrict__ Wf, const float* __restrict__ Wb,
                                                 unsigned short* __restrict__ Pf, unsigned short* __restrict__ Pb) {
  size_t idx = (size_t)blockIdx.x * 256 + threadIdx.x;   // < 1024*1856
  int n = (int)(idx / KP1), k = (int)(idx % KP1);
  const float* W = blockIdx.y ? Wb : Wf;
  unsigned short* Pp = blockIdx.y ? Pb : Pf;
  float v = (n < G4 && k < K1) ? W[(size_t)n * K1 + k] : 0.f;
  Pp[idx] = f2bf(v);
}

__global__ __launch_bounds__(256) void k_pad_w2a(const float* __restrict__ W, unsigned short* __restrict__ Pq) {
  size_t idx = (size_t)blockIdx.x * 256 + threadIdx.x;   // < 512*480
  int n = (int)(idx / KP3), k = (int)(idx % KP3);
  float v = (n < DD && k < DD) ? W[(size_t)n * G4 + k] : 0.f;
  Pq[idx] = f2bf(v);
}

__global__ __launch_bounds__(256) void k_pack_whh(const float* __restrict__ Wf, const float* __restrict__ Wb,
                                                  unsigned int* __restrict__ Pf, unsigned int* __restrict__ Pb) {
  int idx = blockIdx.x * 256 + threadIdx.x;              // < 115*920
  if (idx >= 115 * G4) return;
  int kk = idx / G4, row = idx % G4;
  const float* W = blockIdx.y ? Wb : Wf;
  unsigned int* Pp = blockIdx.y ? Pb : Pf;
  half2v h; h.x = (f16)W[(size_t)row * HH + 2 * kk]; h.y = (f16)W[(size_t)row * HH + 2 * kk + 1];
  Pp[idx] = __builtin_bit_cast(unsigned int, h);
}

__global__ __launch_bounds__(256) void k_pack_bwih(const float* __restrict__ Wf, const float* __restrict__ Wb,
                                                   float* __restrict__ Tf, float* __restrict__ Tb) {
  int idx = blockIdx.x * 256 + threadIdx.x;              // < 460*920
  if (idx >= DD * G4) return;
  int d = idx / G4, row = idx % G4;
  const float* W = blockIdx.y ? Wb : Wf;
  float* T = blockIdx.y ? Tb : Tf;
  T[idx] = W[(size_t)row * DD + d];
}

__global__ __launch_bounds__(256) void k_bias(const float* __restrict__ bihF, const float* __restrict__ bhhF,
                                              const float* __restrict__ bihB, const float* __restrict__ bhhB,
                                              float* __restrict__ biasF, float* __restrict__ biasB) {
  int i = blockIdx.x * 256 + threadIdx.x;
  if (i < G4) {
    if (blockIdx.y == 0) biasF[i] = bihF[i] + bhhF[i];
    else biasB[i] = bihB[i] + bhhB[i];
  }
}

__global__ __launch_bounds__(256) void k_fbpad(unsigned short* __restrict__ FB) {
  int i = blockIdx.x * 256 + threadIdx.x;                // < 16384*20
  int r = i / 20, j = i % 20;
  FB[(size_t)r * LDFB + DD + j] = 0;
}

// sp[p*B+b] = p_features row . w   (also used for sq)
__global__ __launch_bounds__(256) void k_rowdot(const float* __restrict__ M, const float* __restrict__ w,
                                                float* __restrict__ out) {
  int r = blockIdx.x * 4 + (threadIdx.x >> 6);
  int lane = threadIdx.x & 63;
  const float* row = M + (size_t)r * DD;
  float acc = 0.f;
  for (int d = lane; d < DD; d += 64) acc += row[d] * w[d];
#pragma unroll
  for (int d = 1; d < 64; d <<= 1) acc += __shfl_xor(acc, d, 64);
  if (lane == 0) out[r] = acc;
}

// ---------------- fused attention -> final_in (bf16) ----------------
__global__ __launch_bounds__(256) void k_attn(const float* __restrict__ p_feat, const float* __restrict__ q_feat,
                                              const float* __restrict__ score_w, const float* __restrict__ score_b,
                                              const float* __restrict__ sp, const float* __restrict__ sq,
                                              unsigned short* __restrict__ FIp) {
  __shared__ half2v q_s[64 * 230];
  __shared__ half2v p_s[32 * 230];
  __shared__ half2v wpq[230];
  __shared__ float sq_s[64];
  __shared__ float u_row[64];
  __shared__ __align__(16) float w_row[64];
  __shared__ float mxs[1];

  int tid = threadIdx.x;
  int b = blockIdx.y;
  int p0 = blockIdx.x * 32;

  for (int i = tid; i < 230; i += 256) {
    half2v w; w.x = (f16)score_w[2 * DD + 2 * i]; w.y = (f16)score_w[2 * DD + 2 * i + 1];
    wpq[i] = w;
  }
  for (int i = tid; i < 64; i += 256) sq_s[i] = sq[i * BBn + b];
  for (int q = 0; q < 64; q++) {
    for (int i = tid; i < 230; i += 256) {
      float2 f2 = *(const float2*)(q_feat + ((size_t)(q * BBn + b)) * DD + 2 * i);
      half2v v; v.x = (f16)f2.x; v.y = (f16)f2.y;
      q_s[q * 230 + i] = v;
    }
  }
  for (int pl = 0; pl < 32; pl++) {
    for (int i = tid; i < 230; i += 256) {
      float2 f2 = *(const float2*)(p_feat + ((size_t)((p0 + pl) * BBn + b)) * DD + 2 * i);
      half2v v; v.x = (f16)f2.x; v.y = (f16)f2.y;
      p_s[pl * 230 + i] = v;
    }
  }
  __syncthreads();

  float sbias = score_b[0];
  int lane = tid & 63, wv = tid >> 6;
  int myq = tid >> 2, quarter = tid & 3;
  int kb = quarter * 58;
  int ke = (kb + 58 < 230) ? (kb + 58) : 230;

  for (int pl = 0; pl < 32; pl++) {
    // ---- u-dot over d for all q (4 lanes per q) ----
    float acc = 0.f;
    const half2v* prow = p_s + pl * 230;
    const half2v* qrow = q_s + myq * 230;
    for (int k = kb; k < ke; k++) {
      half2v pw = prow[k] * wpq[k];
      acc = dot2f(pw, qrow[k], acc);
    }
    acc += __shfl_xor(acc, 1, 64);
    acc += __shfl_xor(acc, 2, 64);
    if (quarter == 0) u_row[myq] = acc + sp[(p0 + pl) * BBn + b] + sq_s[myq] + sbias;
    __syncthreads();
    // ---- softmax over q (wave 0) ----
    if (wv == 0) {
      float v = u_row[lane];
      float m = v;
#pragma unroll
      for (int d = 1; d < 64; d <<= 1) m = fmaxf(m, __shfl_xor(m, d, 64));
      float e = __expf(v - m);
      float s = e;
#pragma unroll
      for (int d = 1; d < 64; d <<= 1) s += __shfl_xor(s, d, 64);
      w_row[lane] = e / s;
      if (lane == 0) mxs[0] = m;   // c2q = max_q u
    }
    __syncthreads();
    // ---- PV + write final_in ----
    if (tid < 230) {
      float c2q = mxs[0];
      half2v pv = p_s[pl * 230 + tid];
      float nux = 0.f, nuy = 0.f;
      for (int q = 0; q < 64; q += 4) {
        float4 wq = *(const float4*)&w_row[q];
        half2v q0 = q_s[(q + 0) * 230 + tid];
        half2v q1 = q_s[(q + 1) * 230 + tid];
        half2v q2 = q_s[(q + 2) * 230 + tid];
        half2v q3 = q_s[(q + 3) * 230 + tid];
        nux = fmaf(wq.x, (float)q0.x, nux); nuy = fmaf(wq.x, (float)q0.y, nuy);
        nux = fmaf(wq.y, (float)q1.x, nux); nuy = fmaf(wq.y, (float)q1.y, nuy);
        nux = fmaf(wq.z, (float)q2.x, nux); nuy = fmaf(wq.z, (float)q2.y, nuy);
        nux = fmaf(wq.w, (float)q3.x, nux); nuy = fmaf(wq.w, (float)q3.y, nuy);
      }
      float px = (float)pv.x, py = (float)pv.y;
      size_t rr = (size_t)(b * PPn + p0 + pl);
      unsigned short* o = FIp + rr * KP1 + 2 * tid;
      *(unsigned int*)(o +    0) = (unsigned int)f2bf(px)            | ((unsigned int)f2bf(py) << 16);
      *(unsigned int*)(o +  460) = (unsigned int)f2bf(c2q * px)      | ((unsigned int)f2bf(c2q * py) << 16);
      *(unsigned int*)(o +  920) = (unsigned int)f2bf(px * nux)      | ((unsigned int)f2bf(py * nuy) << 16);
      *(unsigned int*)(o + 1380) = (unsigned int)f2bf(c2q * px * px) | ((unsigned int)f2bf(c2q * py * py) << 16);
    } else if (tid < 238) {
      int j = tid - 230;
      size_t rr = (size_t)(b * PPn + p0 + pl);
      *(unsigned int*)(FIp + rr * KP1 + 1840 + 2 * j) = 0u;  // K pad
    }
    __syncthreads();
  }
}

// ---------------- bf16 MFMA GEMM: C[M][Nreal] = A[M][K] * Bw[N][K]^T (+bias) ----------------
__global__ __launch_bounds__(256, 2) void k_gemm(const unsigned short* __restrict__ A, int lda,
                                                 const unsigned short* __restrict__ Bw, int ldb,
                                                 float* __restrict__ C, int ldc,
                                                 int Nreal, int Ktiles, const float* __restrict__ bias) {
  __shared__ unsigned short As[128 * 32];
  __shared__ unsigned short Bs[128 * 32];
  int tid = threadIdx.x;
  int m0 = blockIdx.x * 128, n0 = blockIdx.y * 128;
  int wv = tid >> 6, lane = tid & 63;
  int wr = wv >> 1, wc = wv & 1;
  int laneM = lane & 15, laneK = lane >> 4;

  f32x4_t acc[4][4];
#pragma unroll
  for (int i = 0; i < 4; i++)
#pragma unroll
    for (int j = 0; j < 4; j++) acc[i][j] = (f32x4_t){0.f, 0.f, 0.f, 0.f};

  int row0 = tid >> 2, ch0 = tid & 3;
  int row1 = (256 + tid) >> 2, ch1 = tid & 3;
  const unsigned short* a0 = A + (size_t)(m0 + row0) * lda + ch0 * 8;
  const unsigned short* a1 = A + (size_t)(m0 + row1) * lda + ch1 * 8;
  const unsigned short* b0 = Bw + (size_t)(n0 + row0) * ldb + ch0 * 8;
  const unsigned short* b1 = Bw + (size_t)(n0 + row1) * ldb + ch1 * 8;

  for (int kt = 0; kt < Ktiles; kt++) {
    uint4 av0 = *(const uint4*)a0;
    uint4 av1 = *(const uint4*)a1;
    uint4 bv0 = *(const uint4*)b0;
    uint4 bv1 = *(const uint4*)b1;
    a0 += 32; a1 += 32; b0 += 32; b1 += 32;
    __syncthreads();
    *(uint4*)(As + (size_t)tid * 8)         = av0;
    *(uint4*)(As + (size_t)(256 + tid) * 8) = av1;
    *(uint4*)(Bs + (size_t)tid * 8)         = bv0;
    *(uint4*)(Bs + (size_t)(256 + tid) * 8) = bv1;
    __syncthreads();
    bf16x8_t af[4], bfr[4];
#pragma unroll
    for (int mi = 0; mi < 4; mi++)
      af[mi] = *(const bf16x8_t*)(As + (size_t)(wr * 64 + mi * 16 + laneM) * 32 + laneK * 8);
#pragma unroll
    for (int ni = 0; ni < 4; ni++)
      bfr[ni] = *(const bf16x8_t*)(Bs + (size_t)(wc * 64 + ni * 16 + laneM) * 32 + laneK * 8);
#pragma unroll
    for (int mi = 0; mi < 4; mi++)
#pragma unroll
      for (int ni = 0; ni < 4; ni++)
        acc[mi][ni] = __builtin_amdgcn_mfma_f32_16x16x32_bf16(af[mi], bfr[ni], acc[mi][ni], 0, 0, 0);
  }
#pragma unroll
  for (int mi = 0; mi < 4; mi++)
#pragma unroll
    for (int ni = 0; ni < 4; ni++) {
      int ccol = n0 + wc * 64 + ni * 16 + laneM;
      if (ccol < Nreal) {
        float bv = bias ? bias[ccol] : 0.f;
#pragma unroll
        for (int j = 0; j < 4; j++) {
          int crow = m0 + wr * 64 + mi * 16 + laneK * 4 + j;
          C[(size_t)crow * ldc + ccol] = acc[mi][ni][j] + bv;
        }
      }
    }
}

// ---------------- persistent BiLSTM recurrence ----------------
// 64 WGs: (dir, batch). Whh split: ks 0..103 in VGPRs (208 regs/thread),
// ks 104..114 (+zero pad 115) in per-thread LDS slices (6 ds_read_b128/step).
// OCCUPANCY NOTE (R1-R4 evidence): __launch_bounds__(512,2) and raw
// amdgpu_waves_per_eu(1,2) both produced VGPR_Count=128 -> ~100 weight
// dwords/thread spilled to scratch; k_recur was L2-scratch-BW-bound
// (~3540 cyc/step measured = ~800 scratch loads x 4.4 cyc).
// The observed semantics of __launch_bounds__ 2nd arg = min BLOCKS/CU:
// (512,2) -> 16 waves/CU -> 4 waves/EU -> 512/4 = 128 VGPRs.  So use
// (512,1): 8 waves/CU -> 2 waves/EU -> 256-VGPR budget; demand ~240.
__global__ __launch_bounds__(512, 1)
void k_recur(const unsigned int* __restrict__ WPf,
             const unsigned int* __restrict__ WPb,
             const float* __restrict__ Xf, const float* __restrict__ Xb,
             float* __restrict__ outF, unsigned short* __restrict__ FB) {
  __shared__ unsigned int wlds[460 * 28];   // 51,520 B
  __shared__ unsigned int h2[2][116];
  __shared__ float abuf[232];
  int tid = threadIdx.x;
  int dir = blockIdx.x >> 5, b = blockIdx.x & 31;
  const unsigned int* __restrict__ WP = dir ? WPb : WPf;
  const float* __restrict__ X = dir ? Xb : Xf;

  bool isA = tid < 230;
  bool isB = (tid >= 256) && (tid < 486);
  bool act = isA || isB;
  int u = isA ? tid : (tid - 256);
  int row0 = isA ? u : (HH + u);                // i-row | f-row
  int row1 = isA ? (2 * HH + u) : (3 * HH + u); // g-row | o-row
  int slot = isA ? u : (230 + u);

  half2v w0[104], w1[104];
  if (act) {
#pragma unroll
    for (int k = 0; k < 104; k++) {
      w0[k] = bch2(WP[k * G4 + row0]);
      w1[k] = bch2(WP[k * G4 + row1]);
    }
    // LDS slice: ks 104..114 (+pad 115) interleaved (w0[ka],w1[ka],w0[kb],w1[kb])
    unsigned int* sl = &wlds[slot * 28];
#pragma unroll
    for (int j = 0; j < 6; j++) {
      int ka = 104 + 2 * j, kb2 = 105 + 2 * j;
      sl[4 * j + 0] = WP[ka * G4 + row0];
      sl[4 * j + 1] = WP[ka * G4 + row1];
      sl[4 * j + 2] = (kb2 < 115) ? WP[kb2 * G4 + row0] : 0u;
      sl[4 * j + 3] = (kb2 < 115) ? WP[kb2 * G4 + row1] : 0u;
    }
  }
  for (int i = tid; i < 116; i += 512) { h2[0][i] = 0u; h2[1][i] = 0u; }

  int col0 = u + (isB ? HH : 0);
  int col1 = col0 + 2 * HH;
  float x0 = 0.f, x1 = 0.f;
  if (act) {
    int t0 = dir ? (PPn - 1) : 0;
    const float* xr = X + (size_t)(b * PPn + t0) * G4;
    x0 = xr[col0]; x1 = xr[col1];
  }
  float c = 0.f;
  __syncthreads();

  for (int s = 0; s < PPn; s++) {
    int t = dir ? (PPn - 1 - s) : s;
    float acc0 = x0, acc1 = x1;
    if (act && s < PPn - 1) {
      int tn = dir ? (PPn - 2 - s) : (s + 1);
      const float* xr = X + (size_t)(b * PPn + tn) * G4;
      x0 = xr[col0]; x1 = xr[col1];
    }
    const unsigned int* hb = h2[s & 1];
    if (act) {
      // register part: ks 0..103
#pragma unroll
      for (int ch = 0; ch < 26; ch++) {
        uint4 hv = *(const uint4*)(hb + ch * 4);
        half2v ha = bch2(hv.x);
        half2v hbv = bch2(hv.y);
        half2v hc = bch2(hv.z);
        half2v hd = bch2(hv.w);
        acc0 = dot2f(w0[ch * 4 + 0], ha, acc0);  acc1 = dot2f(w1[ch * 4 + 0], ha, acc1);
        acc0 = dot2f(w0[ch * 4 + 1], hbv, acc0); acc1 = dot2f(w1[ch * 4 + 1], hbv, acc1);
        acc0 = dot2f(w0[ch * 4 + 2], hc, acc0);  acc1 = dot2f(w1[ch * 4 + 2], hc, acc1);
        acc0 = dot2f(w0[ch * 4 + 3], hd, acc0);  acc1 = dot2f(w1[ch * 4 + 3], hd, acc1);
      }
      // LDS-slice part: ks 104..115 (k=115 weight is zero)
      const unsigned int* sl = &wlds[slot * 28];
#pragma unroll
      for (int j = 0; j < 3; j++) {
        uint4 wva = *(const uint4*)(sl + 8 * j);
        uint4 wvb = *(const uint4*)(sl + 8 * j + 4);
        uint4 hv = *(const uint4*)(hb + 104 + 4 * j);
        half2v ha = bch2(hv.x);
        half2v hbv = bch2(hv.y);
        half2v hc = bch2(hv.z);
        half2v hd = bch2(hv.w);
        acc0 = dot2f(bch2(wva.x), ha, acc0);  acc1 = dot2f(bch2(wva.y), ha, acc1);
        acc0 = dot2f(bch2(wva.z), hbv, acc0); acc1 = dot2f(bch2(wva.w), hbv, acc1);
        acc0 = dot2f(bch2(wvb.x), hc, acc0);  acc1 = dot2f(bch2(wvb.y), hc, acc1);
        acc0 = dot2f(bch2(wvb.z), hd, acc0);  acc1 = dot2f(bch2(wvb.w), hd, acc1);
      }
    }
    float ff = 0.f, oo = 0.f;
    if (isA) {
      abuf[u] = sigm(acc0) * tanhfast(acc1);   // sig(i)*tanh(g)
    }
    if (isB) { ff = sigm(acc0); oo = sigm(acc1); }
    __syncthreads();
    if (isB) {
      c = ff * c + abuf[u];
      float hval = oo * tanhfast(c);
      f16* hw = (f16*)(&h2[(s + 1) & 1][0]);
      hw[u] = (f16)hval;
      size_t ro = (size_t)(b * PPn + t);
      outF[ro * DD + dir * HH + u] = hval;
      FB[ro * LDFB + dir * HH + u] = f2bf(hval);
    }
    __syncthreads();
  }
}

// ---------------- ptr scores ----------------
__global__ __launch_bounds__(256) void k_score(const float* __restrict__ Yv, const float* __restrict__ hR,
                                               const float* __restrict__ w1a, const float* __restrict__ w1b,
                                               float* __restrict__ out) {
  int r = blockIdx.x * 4 + (threadIdx.x >> 6);
  int lane = threadIdx.x & 63;
  const float* row = Yv + (size_t)r * DD;
  const float* hrow = hR ? (hR + (size_t)(r >> 9) * DD) : nullptr;
  float acc = 0.f;
  for (int e = lane; e < DD; e += 64) {
    float v = row[e];
    if (hrow) v += hrow[e];
    acc += tanhfast(v) * w1a[e];
  }
#pragma unroll
  for (int d = 1; d < 64; d <<= 1) acc += __shfl_xor(acc, d, 64);
  if (lane == 0) out[r] = acc + w1b[0];
}

__global__ __launch_bounds__(512) void k_softmax(const float* __restrict__ s, float* __restrict__ outLog,
                                                 float* __restrict__ outAlpha) {
  __shared__ float red[8];
  int b = blockIdx.x, t = threadIdx.x;
  int lane = t & 63, wv = t >> 6;
  float v = s[b * PPn + t];
  float m = v;
#pragma unroll
  for (int d = 1; d < 64; d <<= 1) m = fmaxf(m, __shfl_xor(m, d, 64));
  if (lane == 0) red[wv] = m;
  __syncthreads();
  float mall = red[0];
#pragma unroll
  for (int i = 1; i < 8; i++) mall = fmaxf(mall, red[i]);
  __syncthreads();
  float e = __expf(v - mall);
  float sum = e;
#pragma unroll
  for (int d = 1; d < 64; d <<= 1) sum += __shfl_xor(sum, d, 64);
  if (lane == 0) red[wv] = sum;
  __syncthreads();
  float tot = red[0];
#pragma unroll
  for (int i = 1; i < 8; i++) tot += red[i];
  float lz = __logf(tot);
  outLog[b * PPn + t] = v - mall - lz;
  if (outAlpha) outAlpha[b * PPn + t] = e / tot;
}

__global__ __launch_bounds__(256) void k_c1(const float* __restrict__ alpha1, const float* __restrict__ finalF,
                                            float* __restrict__ c1) {
  __shared__ float al[512];
  int b = blockIdx.x, t = threadIdx.x;
  al[t] = alpha1[b * PPn + t];
  al[t + 256] = alpha1[b * PPn + t + 256];
  __syncthreads();
  for (int d = t; d < DD; d += 256) {
    float acc = 0.f;
#pragma unroll 8
    for (int p = 0; p < PPn; p++) acc += al[p] * finalF[((size_t)b * PPn + p) * DD + d];
    c1[b * DD + d] = acc;
  }
}

// single-step b-BiLSTM (h0=c0=0 so Whh and f-gate drop out)
__global__ __launch_bounds__(256) void k_h0a(const float* __restrict__ WTf, const float* __restrict__ WTb,
                                             const float* __restrict__ bihF, const float* __restrict__ bhhF,
                                             const float* __restrict__ bihB, const float* __restrict__ bhhB,
                                             const float* __restrict__ c1, float* __restrict__ h0a) {
  int dir = blockIdx.x >> 5, b = blockIdx.x & 31;
  const float* WT = dir ? WTb : WTf;
  const float* bih = dir ? bihB : bihF;
  const float* bhh = dir ? bhhB : bhhF;
  __shared__ float cs[DD];
  int t = threadIdx.x;
  for (int d = t; d < DD; d += 256) cs[d] = c1[b * DD + d];
  __syncthreads();
  if (t < HH) {
    float gi = bih[t] + bhh[t];
    float gg = bih[2 * HH + t] + bhh[2 * HH + t];
    float go = bih[3 * HH + t] + bhh[3 * HH + t];
    for (int d = 0; d < DD; d++) {
      float cv = cs[d];
      const float* wr2 = WT + (size_t)d * G4;
      gi = fmaf(cv, wr2[t], gi);
      gg = fmaf(cv, wr2[2 * HH + t], gg);
      go = fmaf(cv, wr2[3 * HH + t], go);
    }
    float cc = sigm(gi) * tanhfast(gg);
    h0a[b * DD + dir * HH + t] = sigm(go) * tanhfast(cc);
  }
}

__global__ __launch_bounds__(256) void k_hR(const float* __restrict__ w2a_w, const float* __restrict__ h0a,
                                            float* __restrict__ hR) {
  int b = blockIdx.x, t = threadIdx.x;
  __shared__ float hs[DD];
  for (int d = t; d < DD; d += 256) hs[d] = h0a[b * DD + d];
  __syncthreads();
  for (int e = t; e < DD; e += 256) {
    float acc = 0.f;
    const float* wr2 = w2a_w + (size_t)e * G4 + DD;   // right half of w2a_w row e
    for (int d = 0; d < DD; d++) acc = fmaf(hs[d], wr2[d], acc);
    hR[b * DD + e] = acc;
  }
}

// ---------------- launcher ----------------
extern "C" void kernel_launch(void* const* d_in, const int* in_sizes, int n_in,
                              void* d_out, int out_size, void* d_ws, size_t ws_size,
                              hipStream_t stream) {
  (void)in_sizes; (void)n_in; (void)out_size; (void)ws_size;
  const float* p_feat  = (const float*)d_in[0];
  const float* q_feat  = (const float*)d_in[1];
  const float* score_w = (const float*)d_in[2];
  const float* score_b = (const float*)d_in[3];
  const float* mWihF   = (const float*)d_in[4];
  const float* mWhhF   = (const float*)d_in[5];
  const float* mBihF   = (const float*)d_in[6];
  const float* mBhhF   = (const float*)d_in[7];
  const float* mWihB   = (const float*)d_in[8];
  const float* mWhhB   = (const float*)d_in[9];
  const float* mBihB   = (const float*)d_in[10];
  const float* mBhhB   = (const float*)d_in[11];
  const float* w2a_w   = (const float*)d_in[12];
  const float* w2a_b   = (const float*)d_in[13];
  const float* w1a_w   = (const float*)d_in[14];
  const float* w1a_b   = (const float*)d_in[15];
  const float* bWihF   = (const float*)d_in[16];
  const float* bBihF   = (const float*)d_in[18];
  const float* bBhhF   = (const float*)d_in[19];
  const float* bWihB   = (const float*)d_in[20];
  const float* bBihB   = (const float*)d_in[22];
  const float* bBhhB   = (const float*)d_in[23];

  char* ws = (char*)d_ws;
  float* XF = (float*)(ws + OFF_XF);
  float* XB = (float*)(ws + OFF_XB);
  unsigned short* FI = (unsigned short*)(ws + OFF_FI);
  float* Yv = (float*)(ws + OFF_Y);
  unsigned short* FB = (unsigned short*)(ws + OFF_FB);
  unsigned short* WFP = (unsigned short*)(ws + OFF_WFP);
  unsigned short* WBP = (unsigned short*)(ws + OFF_WBP);
  unsigned short* W2P = (unsigned short*)(ws + OFF_W2P);
  unsigned int* WPF = (unsigned int*)(ws + OFF_WPF);
  unsigned int* WPB = (unsigned int*)(ws + OFF_WPB);
  float* WTF = (float*)(ws + OFF_WTF);
  float* WTB = (float*)(ws + OFF_WTB);
  float* BIASF = (float*)(ws + OFF_BIASF);
  float* BIASB = (float*)(ws + OFF_BIASB);
  float* SP = (float*)(ws + OFF_SP);
  float* SQ = (float*)(ws + OFF_SQ);
  float* S1 = (float*)(ws + OFF_S1);
  float* AL1 = (float*)(ws + OFF_AL1);
  float* C1 = (float*)(ws + OFF_C1);
  float* H0A = (float*)(ws + OFF_H0A);
  float* HR = (float*)(ws + OFF_HR);
  float* S2 = (float*)(ws + OFF_S2);

  float* outF = (float*)d_out;
  float* outLA1 = outF + (size_t)BBn * PPn * DD;
  float* outA2 = outLA1 + (size_t)BBn * PPn;

  // prep
  k_pad_wih<<<dim3(7424, 2), 256, 0, stream>>>(mWihF, mWihB, WFP, WBP);
  k_pad_w2a<<<dim3(960), 256, 0, stream>>>(w2a_w, W2P);
  k_pack_whh<<<dim3(414, 2), 256, 0, stream>>>(mWhhF, mWhhB, WPF, WPB);
  k_pack_bwih<<<dim3(1654, 2), 256, 0, stream>>>(bWihF, bWihB, WTF, WTB);
  k_bias<<<dim3(4, 2), 256, 0, stream>>>(mBihF, mBhhF, mBihB, mBhhB, BIASF, BIASB);
  k_fbpad<<<dim3(1280), 256, 0, stream>>>(FB);
  k_rowdot<<<dim3(4096), 256, 0, stream>>>(p_feat, score_w, SP);
  k_rowdot<<<dim3(512), 256, 0, stream>>>(q_feat, score_w + DD, SQ);
  // attention -> final_in
  k_attn<<<dim3(16, 32), 256, 0, stream>>>(p_feat, q_feat, score_w, score_b, SP, SQ, FI);
  // big input-projection GEMMs
  k_gemm<<<dim3(128, 8), 256, 0, stream>>>(FI, KP1, WFP, KP1, XF, G4, G4, 58, BIASF);
  k_gemm<<<dim3(128, 8), 256, 0, stream>>>(FI, KP1, WBP, KP1, XB, G4, G4, 58, BIASB);
  // recurrence -> final (d_out) + final bf16
  k_recur<<<dim3(64), 512, 0, stream>>>(WPF, WPB, XF, XB, outF, FB);
  // ptr GEMM: Y = final @ W2aL^T + w2a_b
  k_gemm<<<dim3(128, 4), 256, 0, stream>>>(FB, KP3, W2P, KP3, Yv, DD, DD, 15, w2a_b);
  // s1 -> softmax -> c1
  k_score<<<dim3(4096), 256, 0, stream>>>(Yv, nullptr, w1a_w, w1a_b, S1);
  k_softmax<<<dim3(32), 512, 0, stream>>>(S1, outLA1, AL1);
  k_c1<<<dim3(32), 256, 0, stream>>>(AL1, outF, C1);
  // boundary BiLSTM (1 step) -> h0a -> hR
  k_h0a<<<dim3(64), 256, 0, stream>>>(WTF, WTB, bBihF, bBhhF, bBihB, bBhhB, C1, H0A);
  k_hR<<<dim3(32), 256, 0, stream>>>(w2a_w, H0A, HR);
  // s2 -> log_softmax
  k_score<<<dim3(4096), 256, 0, stream>>>(Yv, HR, w1a_w, w1a_b, S2);
  k_softmax<<<dim3(32), 512, 0, stream>>>(S2, outA2, nullptr);
}